// Round 6
// baseline (673.995 us; speedup 1.0000x reference)
//
#include <hip/hip_runtime.h>
#include <stdint.h>

typedef short short8 __attribute__((ext_vector_type(8)));
typedef short short4v __attribute__((ext_vector_type(4)));
typedef float floatx4 __attribute__((ext_vector_type(4)));

#define H_  8
#define NB_ 4      // batch N
#define S_  1024
#define D_  512
#define KD_ 64

__device__ __forceinline__ short f2bf(float f){
    unsigned u = __builtin_bit_cast(unsigned, f);
    u += 0x7fffu + ((u>>16)&1u);
    return (short)(u>>16);
}
__device__ __forceinline__ float wred_addf(float x){
    #pragma unroll
    for(int o=32;o>0;o>>=1) x += __shfl_xor(x,o,64);
    return x;
}
__device__ __forceinline__ float wred_maxf(float x){
    #pragma unroll
    for(int o=32;o>0;o>>=1) x = fmaxf(x,__shfl_xor(x,o,64));
    return x;
}
// monotone 16-bit key for a bf16 pattern; key 0 <=> 0xFFFF (-NaN) which real scores never hit
__device__ __forceinline__ unsigned bkey(unsigned u){
    return (u & 0x8000u) ? ((~u) & 0xffffu) : (u | 0x8000u);
}
__device__ __forceinline__ float key2f(unsigned k){
    unsigned u = (k & 0x8000u) ? (k & 0x7fffu) : ((~k) & 0xffffu);
    return __builtin_bit_cast(float, u<<16);
}

// ---------------- elementwise fp32 -> bf16 ----------------
__global__ __launch_bounds__(256) void cvt_bf16_kernel(const float* __restrict__ in,
                                                       short* __restrict__ out, int n){
    int i = (blockIdx.x*256 + threadIdx.x)*4;
    if (i + 3 < n){
        floatx4 v = *(const floatx4*)(in + i);
        short4v r;
        #pragma unroll
        for(int j=0;j<4;j++) r[j] = f2bf(v[j]);
        *(short4v*)(out + i) = r;
    }
}

// ---------------- weight transpose + convert: in [R][C] f32 -> out [C][R] bf16 ----------------
__global__ __launch_bounds__(256) void wtrans_kernel(const float* __restrict__ in, short* __restrict__ out,
                                                     int R, int C, long inB, long outB){
    __shared__ float t[32][33];
    int z = blockIdx.z;
    const float* ip = in + (long)z*inB;
    short* op = out + (long)z*outB;
    int c0 = blockIdx.x*32, r0 = blockIdx.y*32;
    int tid = threadIdx.x;
    int r = tid>>3, cq = (tid&7)*4;
    #pragma unroll
    for(int i=0;i<4;i++) t[r][cq+i] = ip[(long)(r0+r)*C + c0+cq+i];
    __syncthreads();
    int c = tid>>3, rq = (tid&7)*4;
    #pragma unroll
    for(int i=0;i<4;i++) op[(long)(c0+c)*R + r0+rq+i] = f2bf(t[rq+i][c]);
}

// ---------------- row softmax of the two graphs ----------------
__global__ __launch_bounds__(256) void graph_softmax_kernel(const float* __restrict__ g0,
                                                            const float* __restrict__ g1,
                                                            float* __restrict__ o0,
                                                            float* __restrict__ o1){
    int row = blockIdx.x;
    const float* g = blockIdx.y ? g1 : g0;
    float* o = blockIdx.y ? o1 : o0;
    const float* gr = g + (long)row*S_;
    float* orow = o + (long)row*S_;
    int tid = threadIdx.x, wave = tid>>6, lane = tid&63;
    __shared__ float red[8];
    float v[4]; float mx = -3.0e38f;
    #pragma unroll
    for(int i=0;i<4;i++){ v[i] = gr[tid + 256*i]; mx = fmaxf(mx, v[i]); }
    mx = wred_maxf(mx);
    if(lane==0) red[wave] = mx;
    __syncthreads();
    mx = fmaxf(fmaxf(red[0],red[1]), fmaxf(red[2],red[3]));
    float s = 0.f;
    #pragma unroll
    for(int i=0;i<4;i++){ v[i] = __expf(v[i]-mx); s += v[i]; }
    s = wred_addf(s);
    if(lane==0) red[4+wave] = s;
    __syncthreads();
    s = red[4]+red[5]+red[6]+red[7];
    float inv = 1.f/s;
    #pragma unroll
    for(int i=0;i<4;i++) orow[tid + 256*i] = v[i]*inv;
}

// ---------------- small bf16 MFMA GEMM (direct-global) ----------------
// mode 0: f32 out [M][N]; 1: bf16 out [M][N]
// mode 2: bf16 K/Q layout out[((z*4 + m>>10)*1024 + (m&1023))*64 + n]   (N==64)
// mode 3: bf16 Vt layout  out[((z*4 + m>>10)*64 + n)*1024 + (m&1023)]  (N==64)
// mode 4: bf16 scores out[(z<<20) + m*1024 + n] = v*0.125 (relu param = causal: skip fully-masked tiles)
__global__ __launch_bounds__(256) void gemm_kernel(
    const short* __restrict__ A, const short* __restrict__ Bt, const float* __restrict__ bias,
    void* __restrict__ out, int M, int N, int K,
    long batchA, long batchB, long batchBias, int mode, int relu)
{
    int m0 = blockIdx.x*64, n0 = blockIdx.y*64;
    if(mode==4 && relu && n0 > m0+63) return;   // fully causal-masked tile
    int z = blockIdx.z;
    const short* Ab = A + (long)z*batchA;
    const short* Bb = Bt + (long)z*batchB;
    const float* bb = bias + (long)z*batchBias;
    int tid = threadIdx.x, wave = tid>>6, lane = tid&63;
    int quad = lane>>4, nl = lane&15;
    int wm = (wave&1)*32, wn = (wave>>1)*32;
    floatx4 acc[2][2];
    #pragma unroll
    for(int i=0;i<2;i++)
        #pragma unroll
        for(int j=0;j<2;j++) acc[i][j] = (floatx4){0.f,0.f,0.f,0.f};

    const short* Aptr0 = Ab + (long)(m0 + wm + nl)*K + quad*8;
    const short* Aptr1 = Aptr0 + 16*(long)K;
    const short* Bptr0 = Bb + (long)(n0 + wn + nl)*K + quad*8;
    const short* Bptr1 = Bptr0 + 16*(long)K;

    for(int k0=0;k0<K;k0+=32){
        short8 a0 = *(const short8*)(Aptr0 + k0);
        short8 a1 = *(const short8*)(Aptr1 + k0);
        short8 b0 = *(const short8*)(Bptr0 + k0);
        short8 b1 = *(const short8*)(Bptr1 + k0);
        acc[0][0] = __builtin_amdgcn_mfma_f32_16x16x32_bf16(a0,b0,acc[0][0],0,0,0);
        acc[0][1] = __builtin_amdgcn_mfma_f32_16x16x32_bf16(a0,b1,acc[0][1],0,0,0);
        acc[1][0] = __builtin_amdgcn_mfma_f32_16x16x32_bf16(a1,b0,acc[1][0],0,0,0);
        acc[1][1] = __builtin_amdgcn_mfma_f32_16x16x32_bf16(a1,b1,acc[1][1],0,0,0);
    }
    #pragma unroll
    for(int i=0;i<2;i++){
        #pragma unroll
        for(int j=0;j<2;j++){
            int n = n0 + wn + j*16 + nl;
            float bv = (mode==4) ? 0.f : bb[n];
            #pragma unroll
            for(int r=0;r<4;r++){
                int m = m0 + wm + i*16 + quad*4 + r;
                float v = acc[i][j][r] + bv;
                if(mode!=4 && relu) v = fmaxf(v, 0.f);
                if(mode==0)      ((float*)out)[(long)m*N + n] = v;
                else if(mode==1) ((short*)out)[(long)m*N + n] = f2bf(v);
                else if(mode==2) ((short*)out)[ ((long)(z*NB_ + (m>>10))*S_ + (m&1023))*KD_ + n ] = f2bf(v);
                else if(mode==3) ((short*)out)[ ((long)(z*NB_ + (m>>10))*KD_ + n)*S_ + (m&1023) ] = f2bf(v);
                else             ((short*)out)[ ((long)z<<20) + (long)m*1024 + n ] = f2bf(v*0.125f);
            }
        }
    }
}

// ---------------- big MFMA GEMM, m97 pattern ----------------
template<int TM, int TN, int OUTBF, int RELU>
__global__ __launch_bounds__(256) void gemm_big_kernel(
    const short* __restrict__ A, const short* __restrict__ Bt, const float* __restrict__ bias,
    void* __restrict__ out, int M, int N, int K)
{
    __shared__ short As[TM*32];
    __shared__ short Bs[TN*32];
    int m0 = blockIdx.x*TM, n0 = blockIdx.y*TN;
    int tid = threadIdx.x, wave = tid>>6, lane = tid&63, quad = lane>>4, nl = lane&15;
    constexpr int MI = TM/32, NI = TN/32;
    int wm = (wave&1)*(TM/2), wn = (wave>>1)*(TN/2);
    floatx4 acc[MI][NI];
    #pragma unroll
    for(int i=0;i<MI;i++)
        #pragma unroll
        for(int j=0;j<NI;j++) acc[i][j] = (floatx4){0.f,0.f,0.f,0.f};

    int r = tid>>2, c = (tid&3)*8;
    for(int k0=0;k0<K;k0+=32){
        __syncthreads();
        #pragma unroll
        for(int i=0;i<TM/64;i++)
            __builtin_amdgcn_global_load_lds(
                (const __attribute__((address_space(1))) unsigned*)(A + (long)(m0 + r + i*64)*K + k0 + c),
                (__attribute__((address_space(3))) unsigned*)((char*)As + i*4096 + wave*1024),
                16, 0, 0);
        #pragma unroll
        for(int i=0;i<TN/64;i++)
            __builtin_amdgcn_global_load_lds(
                (const __attribute__((address_space(1))) unsigned*)(Bt + (long)(n0 + r + i*64)*K + k0 + c),
                (__attribute__((address_space(3))) unsigned*)((char*)Bs + i*4096 + wave*1024),
                16, 0, 0);
        __syncthreads();
        short8 af[MI], bfr[NI];
        #pragma unroll
        for(int i=0;i<MI;i++) af[i] = *(const short8*)(As + (wm + i*16 + nl)*32 + quad*8);
        #pragma unroll
        for(int j=0;j<NI;j++) bfr[j] = *(const short8*)(Bs + (wn + j*16 + nl)*32 + quad*8);
        #pragma unroll
        for(int i=0;i<MI;i++)
            #pragma unroll
            for(int j=0;j<NI;j++)
                acc[i][j] = __builtin_amdgcn_mfma_f32_16x16x32_bf16(af[i],bfr[j],acc[i][j],0,0,0);
    }
    #pragma unroll
    for(int j=0;j<NI;j++){
        int n = n0 + wn + j*16 + nl;
        float bv = bias[n];
        #pragma unroll
        for(int i=0;i<MI;i++){
            #pragma unroll
            for(int rr=0;rr<4;rr++){
                int m = m0 + wm + i*16 + quad*4 + rr;
                float v = acc[i][j][rr] + bv;
                if(RELU) v = fmaxf(v, 0.f);
                if(OUTBF) ((short*)out)[(long)m*N + n] = f2bf(v);
                else      ((float*)out)[(long)m*N + n] = v;
            }
        }
    }
}

// ---------------- K2: selection + softmax + graph blend + PV ----------------
// S: bf16 [hn][1024 q][1024 s] (pre-scaled); Vt: bf16 [hn][64][1024]; graph f32 softmaxed.
// Block: 16 q-rows (qt=blockIdx.x), hn=blockIdx.y. 4 waves, 4 rows/wave, ILP-4 16-bit bisection.
// att staged bf16 in LDS rows rot 8*row, then PV MFMA. ctx: [(n*S+q)*512 + h*64 + v].
__global__ __launch_bounds__(256) void attn_sel_pv_kernel(
    const short* __restrict__ S, const short* __restrict__ Vt,
    const float* __restrict__ graph, short* __restrict__ ctx, int causal)
{
    __shared__ short attb[16*1024];   // 32 KiB
    int qt = blockIdx.x, hn = blockIdx.y;
    int h = hn>>2, n = hn&3;
    int tid=threadIdx.x, wave=tid>>6, lane=tid&63, quad=lane>>4, nl=lane&15;

    unsigned mv[4][16];
    unsigned mk[4];
    // ---- load 4 rows' scores (blocked: lane owns s in [16*lane, 16*lane+16)) -> 16-bit keys ----
    #pragma unroll
    for(int rr=0;rr<4;rr++){
        int qr = wave*4 + rr;
        int qg = qt*16 + qr;
        const short* srow = S + ((long)hn<<20) + (long)qg*1024 + lane*16;
        short8 sv0 = *(const short8*)(srow);
        short8 sv1 = *(const short8*)(srow + 8);
        int slimit = causal ? qg : 1023;
        unsigned m = 0u;
        #pragma unroll
        for(int j=0;j<8;j++){
            int s = lane*16 + j;
            unsigned k = (s<=slimit) ? bkey((unsigned)(unsigned short)sv0[j]) : 0u;
            mv[rr][j] = k; m = (k>m)?k:m;
        }
        #pragma unroll
        for(int j=0;j<8;j++){
            int s = lane*16 + 8 + j;
            unsigned k = (s<=slimit) ? bkey((unsigned)(unsigned short)sv1[j]) : 0u;
            mv[rr][8+j] = k; m = (k>m)?k:m;
        }
        mk[rr] = m;
    }
    // ---- wave max of keys (ILP-4) ----
    #pragma unroll
    for(int o=32;o>0;o>>=1){
        #pragma unroll
        for(int rr=0;rr<4;rr++){
            unsigned t = __shfl_xor(mk[rr],o,64);
            mk[rr] = (t>mk[rr])?t:mk[rr];
        }
    }
    unsigned lo[4], hi[4];
    #pragma unroll
    for(int rr=0;rr<4;rr++){ lo[rr]=0u; hi[rr]=mk[rr]+1u; }
    // ---- exact 16-bit bisection, 4 rows interleaved, counts packed 2x16-bit ----
    while( ((hi[0]-lo[0])>1u) | ((hi[1]-lo[1])>1u) | ((hi[2]-lo[2])>1u) | ((hi[3]-lo[3])>1u) ){
        unsigned mid[4];
        #pragma unroll
        for(int rr=0;rr<4;rr++) mid[rr] = lo[rr] + ((hi[rr]-lo[rr])>>1);
        unsigned p0=0u, p1=0u;
        #pragma unroll
        for(int j=0;j<16;j++){
            p0 += (unsigned)(mv[0][j]>=mid[0]) + ((unsigned)(mv[1][j]>=mid[1])<<16);
            p1 += (unsigned)(mv[2][j]>=mid[2]) + ((unsigned)(mv[3][j]>=mid[3])<<16);
        }
        #pragma unroll
        for(int o=32;o>0;o>>=1){ p0 += __shfl_xor(p0,o,64); p1 += __shfl_xor(p1,o,64); }
        unsigned c[4] = { p0&0xffffu, p0>>16, p1&0xffffu, p1>>16 };
        #pragma unroll
        for(int rr=0;rr<4;rr++){
            if(hi[rr]-lo[rr] > 1u){
                if(c[rr] >= 128u){ lo[rr] = mid[rr]; if(c[rr] == 128u) hi[rr] = mid[rr]+1u; }
                else hi[rr] = mid[rr];
            }
        }
    }
    // ---- sums (exp computed on the fly, recomputed at blend to save regs) ----
    float mxf[4], sm[4];
    #pragma unroll
    for(int rr=0;rr<4;rr++){
        mxf[rr] = key2f(mk[rr]);
        float s_ = 0.f;
        #pragma unroll
        for(int j=0;j<16;j++){
            unsigned k = mv[rr][j];
            if(k >= lo[rr] && k != 0u) s_ += __expf(key2f(k) - mxf[rr]);
        }
        sm[rr] = s_;
    }
    #pragma unroll
    for(int o=32;o>0;o>>=1){
        #pragma unroll
        for(int rr=0;rr<4;rr++) sm[rr] += __shfl_xor(sm[rr],o,64);
    }
    // ---- blend with graph, write bf16 att to LDS (rot 8*qr) ----
    #pragma unroll
    for(int rr=0;rr<4;rr++){
        int qr = wave*4 + rr;
        int qg = qt*16 + qr;
        float inv = 0.5f/sm[rr];
        const float* grow = graph + (long)qg*1024 + lane*16;
        floatx4 g0 = *(const floatx4*)(grow);
        floatx4 g1 = *(const floatx4*)(grow+4);
        floatx4 g2 = *(const floatx4*)(grow+8);
        floatx4 g3 = *(const floatx4*)(grow+12);
        short8 o0, o1;
        #pragma unroll
        for(int j=0;j<8;j++){
            unsigned k = mv[rr][j];
            float e = (k >= lo[rr] && k != 0u) ? __expf(key2f(k)-mxf[rr]) : 0.f;
            float gv = (j<4) ? g0[j] : g1[j-4];
            o0[j] = f2bf(0.5f*gv + e*inv);
        }
        #pragma unroll
        for(int j=0;j<8;j++){
            unsigned k = mv[rr][8+j];
            float e = (k >= lo[rr] && k != 0u) ? __expf(key2f(k)-mxf[rr]) : 0.f;
            float gv = (j<4) ? g2[j] : g3[j-4];
            o1[j] = f2bf(0.5f*gv + e*inv);
        }
        int base = (lane*16 + 8*qr) & 1023;
        *(short8*)(attb + qr*1024 + base) = o0;
        *(short8*)(attb + qr*1024 + ((base+8)&1023)) = o1;
    }
    __syncthreads();
    // ---- PV: ctx = att @ V ----
    int v0 = wave*16;
    const short* Vp = Vt + ((long)hn*KD_ + v0 + nl)*S_;
    floatx4 o4 = (floatx4){0.f,0.f,0.f,0.f};
    int arow = nl;
    for(int s0=0; s0<1024; s0+=32){
        int cs = (s0 + quad*8 + 8*arow) & 1023;
        short8 ap = *(const short8*)(attb + arow*1024 + cs);
        short8 bv = *(const short8*)(Vp + s0 + quad*8);
        o4 = __builtin_amdgcn_mfma_f32_16x16x32_bf16(ap,bv,o4,0,0,0);
    }
    #pragma unroll
    for(int rr=0;rr<4;rr++){
        int q = quad*4 + rr;
        ctx[ ((long)(n*S_ + qt*16 + q))*512 + h*KD_ + v0 + nl ] = f2bf(o4[rr]);
    }
}

// ---------------- fused attention (R5 fallback, used when ws is too small) ----------------
__global__ __launch_bounds__(256) void attn_kernel(
    const short* __restrict__ Qb, const short* __restrict__ Kb, const short* __restrict__ Vt,
    const float* __restrict__ graph, short* __restrict__ ctx, int causal)
{
    __shared__ float sc[8*1024];
    int qt = blockIdx.x, hn = blockIdx.y;
    int h = hn>>2, n = hn&3;
    int q0 = qt*8;
    int tid=threadIdx.x, wave=tid>>6, lane=tid&63, quad=lane>>4, nl=lane&15;

    const short* Qp = Qb + ((long)hn*S_ + q0 + (nl&7))*KD_ + quad*8;
    short8 aq0 = *(const short8*)(Qp);
    short8 aq1 = *(const short8*)(Qp + 32);
    const short* Kp = Kb + (long)hn*S_*KD_;
    int stmax = causal ? ((q0+7)>>4) : 63;
    for(int st=wave; st<=stmax; st+=4){
        const short* kp = Kp + (st*16 + nl)*KD_ + quad*8;
        short8 b0 = *(const short8*)(kp);
        short8 b1 = *(const short8*)(kp + 32);
        floatx4 cc = (floatx4){0.f,0.f,0.f,0.f};
        cc = __builtin_amdgcn_mfma_f32_16x16x32_bf16(aq0,b0,cc,0,0,0);
        cc = __builtin_amdgcn_mfma_f32_16x16x32_bf16(aq1,b1,cc,0,0,0);
        #pragma unroll
        for(int rr=0;rr<4;rr++){
            int q = quad*4 + rr, s = st*16 + nl;
            if(q < 8) sc[q*1024 + ((s + q*4)&1023)] = cc[rr]*0.125f;
        }
    }
    __syncthreads();

    short* attb = (short*)sc;
    {
        int qb = wave*2;
        unsigned mv[2][16];
        float g[2][16];
        float mx[2];
        #pragma unroll
        for(int rr=0;rr<2;rr++){
            const float* grow = graph + (long)(q0 + qb + rr)*S_;
            #pragma unroll
            for(int j=0;j<16;j++) g[rr][j] = grow[lane + 64*j];
        }
        #pragma unroll
        for(int rr=0;rr<2;rr++){
            int q = qb + rr;
            int slimit = causal ? (q0 + q) : 1023;
            float m = -3.0e38f;
            #pragma unroll
            for(int j=0;j<16;j++){
                int s = lane + 64*j;
                float x = (s<=slimit) ? sc[q*1024 + ((s + q*4)&1023)] : -__builtin_inff();
                m = fmaxf(m, x);
                unsigned u = __builtin_bit_cast(unsigned, x);
                mv[rr][j] = (u>>31) ? ~u : (u | 0x80000000u);
            }
            mx[rr] = m;
        }
        __syncthreads();
        #pragma unroll
        for(int o=32;o>0;o>>=1){
            #pragma unroll
            for(int rr=0;rr<2;rr++) mx[rr] = fmaxf(mx[rr], __shfl_xor(mx[rr],o,64));
        }
        unsigned lo[2], hi[2];
        #pragma unroll
        for(int rr=0;rr<2;rr++){
            unsigned um = __builtin_bit_cast(unsigned, mx[rr]);
            um = (um>>31) ? ~um : (um | 0x80000000u);
            lo[rr] = 0u; hi[rr] = um + 1u;
        }
        while( ((hi[0]-lo[0])>1u) | ((hi[1]-lo[1])>1u) ){
            unsigned mid0 = lo[0] + ((hi[0]-lo[0])>>1);
            unsigned mid1 = lo[1] + ((hi[1]-lo[1])>>1);
            unsigned p = 0u;
            #pragma unroll
            for(int j=0;j<16;j++)
                p += (unsigned)(mv[0][j]>=mid0) + ((unsigned)(mv[1][j]>=mid1)<<16);
            #pragma unroll
            for(int o=32;o>0;o>>=1) p += __shfl_xor(p,o,64);
            unsigned c0 = p & 0xffffu, c1 = p >> 16;
            if(hi[0]-lo[0] > 1u){
                if(c0 >= 128u){ lo[0] = mid0; if(c0 == 128u) hi[0] = mid0 + 1u; }
                else hi[0] = mid0;
            }
            if(hi[1]-lo[1] > 1u){
                if(c1 >= 128u){ lo[1] = mid1; if(c1 == 128u) hi[1] = mid1 + 1u; }
                else hi[1] = mid1;
            }
        }
        float sm[2];
        #pragma unroll
        for(int rr=0;rr<2;rr++){
            float s_ = 0.f;
            #pragma unroll
            for(int j=0;j<16;j++){
                unsigned k = mv[rr][j];
                unsigned u = (k>>31) ? (k & 0x7fffffffu) : ~k;
                float x = __builtin_bit_cast(float, u);
                float ee = (k >= lo[rr]) ? __expf(x - mx[rr]) : 0.f;
                mv[rr][j] = __builtin_bit_cast(unsigned, ee);
                s_ += ee;
            }
            sm[rr] = s_;
        }
        #pragma unroll
        for(int o=32;o>0;o>>=1){
            #pragma unroll
            for(int rr=0;rr<2;rr++) sm[rr] += __shfl_xor(sm[rr],o,64);
        }
        #pragma unroll
        for(int rr=0;rr<2;rr++){
            int q = qb + rr;
            float inv = 0.5f/sm[rr];
            #pragma unroll
            for(int j=0;j<16;j++){
                int s = lane + 64*j;
                float ee = __builtin_bit_cast(float, mv[rr][j]);
                attb[q*1024 + ((s + q*8)&1023)] = f2bf(0.5f*g[rr][j] + ee*inv);
            }
        }
    }
    __syncthreads();

    int v0 = wave*16;
    const short* Vp = Vt + ((long)hn*KD_ + v0 + nl)*S_;
    floatx4 o4 = (floatx4){0.f,0.f,0.f,0.f};
    int qrow = nl & 7;
    for(int s0=0; s0<1024; s0+=32){
        int cs = (s0 + quad*8 + qrow*8) & 1023;
        short8 ap = *(const short8*)(attb + qrow*1024 + cs);
        short8 bv = *(const short8*)(Vp + s0 + quad*8);
        o4 = __builtin_amdgcn_mfma_f32_16x16x32_bf16(ap,bv,o4,0,0,0);
    }
    #pragma unroll
    for(int rr=0;rr<4;rr++){
        int q = quad*4 + rr;
        if(q < 8)
            ctx[ ((long)(n*S_ + q0 + q))*512 + h*KD_ + v0 + nl ] = f2bf(o4[rr]);
    }
}

// ---------------- LayerNorm(x + res) ----------------
__global__ __launch_bounds__(256) void ln_kernel(const float* __restrict__ x, const float* __restrict__ res,
                                                 float* __restrict__ outf, short* __restrict__ outb){
    long row = blockIdx.x;
    const float* xr = x + row*D_;
    const float* rr = res + row*D_;
    int tid = threadIdx.x, wave = tid>>6, lane = tid&63;
    float t0 = xr[tid] + rr[tid];
    float t1 = xr[tid+256] + rr[tid+256];
    float s = t0 + t1, s2 = t0*t0 + t1*t1;
    __shared__ float red[8];
    s = wred_addf(s); s2 = wred_addf(s2);
    if(lane==0){ red[wave] = s; red[4+wave] = s2; }
    __syncthreads();
    s  = red[0]+red[1]+red[2]+red[3];
    s2 = red[4]+red[5]+red[6]+red[7];
    float mean = s*(1.f/512.f);
    float var = s2*(1.f/512.f) - mean*mean;
    float rs = rsqrtf(var + 1e-5f);
    float o0 = (t0-mean)*rs, o1 = (t1-mean)*rs;
    if(outf){ outf[row*D_+tid] = o0; outf[row*D_+tid+256] = o1; }
    if(outb){ outb[row*D_+tid] = f2bf(o0); outb[row*D_+tid+256] = f2bf(o1); }
}

extern "C" void kernel_launch(void* const* d_in, const int* in_sizes, int n_in,
                              void* d_out, int out_size, void* d_ws, size_t ws_size,
                              hipStream_t stream)
{
    const float* z         = (const float*)d_in[0];
    const float* y         = (const float*)d_in[1];
    const float* graph_dec = (const float*)d_in[2];
    const float* graph_enc = (const float*)d_in[3];
    const float* dec_Wk = (const float*)d_in[4];  const float* dec_bk = (const float*)d_in[5];
    const float* dec_Wv = (const float*)d_in[6];  const float* dec_bv = (const float*)d_in[7];
    const float* dec_Wo = (const float*)d_in[8];  const float* dec_bo = (const float*)d_in[9];
    const float* enc_Wk = (const float*)d_in[10]; const float* enc_bk = (const float*)d_in[11];
    const float* enc_Wq = (const float*)d_in[12]; const float* enc_bq = (const float*)d_in[13];
    const float* enc_Wv = (const float*)d_in[14]; const float* enc_bv = (const float*)d_in[15];
    const float* enc_Wo = (const float*)d_in[16]; const float* enc_bo = (const float*)d_in[17];
    const float* fc_W1  = (const float*)d_in[18]; const float* fc_b1  = (const float*)d_in[19];
    const float* fc_W2  = (const float*)d_in[20]; const float* fc_b2  = (const float*)d_in[21];

    char* ws = (char*)d_ws;
    float* gdec  = (float*)(ws + 0x0000000);
    float* genc  = (float*)(ws + 0x0400000);
    short* y_bf  = (short*)(ws + 0x0800000);
    short* z_bf  = (short*)(ws + 0x0C00000);
    short* Kdec  = (short*)(ws + 0x1000000);
    short* Vtdec = (short*)(ws + 0x1400000);
    short* Kenc  = (short*)(ws + 0x1800000);
    short* Vtenc = (short*)(ws + 0x1C00000);
    short* Qenc  = (short*)(ws + 0x2000000);
    short* ctx   = (short*)(ws + 0x2400000);
    float* tmp   = (float*)(ws + 0x2800000);
    float* hbuf  = (float*)(ws + 0x3000000);
    short* h_bf  = (short*)(ws + 0x3800000);
    float* h2    = (float*)(ws + 0x3C00000);
    short* h2_bf = (short*)(ws + 0x4400000);
    short* fc1   = (short*)(ws + 0x4800000);
    short* wKdt  = (short*)(ws + 0x5800000);
    short* wVdt  = (short*)(ws + 0x5880000);
    short* wOdt  = (short*)(ws + 0x5900000);
    short* wKet  = (short*)(ws + 0x5980000);
    short* wQet  = (short*)(ws + 0x5A00000);
    short* wVet  = (short*)(ws + 0x5A80000);
    short* wOet  = (short*)(ws + 0x5B00000);
    short* wF1t  = (short*)(ws + 0x5B80000);
    short* wF2t  = (short*)(ws + 0x5D80000);
    short* Sbuf  = (short*)(ws + 0x6000000);   // 64 MB bf16 scores
    float* outp  = (float*)d_out;
    bool big = ws_size >= 0xA000000ull;        // need 160 MB for the split path

    dim3 B(256);
    // weight transposes -> bf16 [N][K]
    wtrans_kernel<<<dim3(2,16,8),  B,0,stream>>>(dec_Wk, wKdt, 512,  64, 512*64, 64*512);
    wtrans_kernel<<<dim3(2,16,8),  B,0,stream>>>(dec_Wv, wVdt, 512,  64, 512*64, 64*512);
    wtrans_kernel<<<dim3(16,16,1), B,0,stream>>>(dec_Wo, wOdt, 512, 512, 0, 0);
    wtrans_kernel<<<dim3(2,16,8),  B,0,stream>>>(enc_Wk, wKet, 512,  64, 512*64, 64*512);
    wtrans_kernel<<<dim3(2,16,8),  B,0,stream>>>(enc_Wq, wQet, 512,  64, 512*64, 64*512);
    wtrans_kernel<<<dim3(2,16,8),  B,0,stream>>>(enc_Wv, wVet, 512,  64, 512*64, 64*512);
    wtrans_kernel<<<dim3(16,16,1), B,0,stream>>>(enc_Wo, wOet, 512, 512, 0, 0);
    wtrans_kernel<<<dim3(64,16,1), B,0,stream>>>(fc_W1,  wF1t, 512,2048, 0, 0);
    wtrans_kernel<<<dim3(16,64,1), B,0,stream>>>(fc_W2,  wF2t,2048, 512, 0, 0);
    cvt_bf16_kernel<<<dim3(2048),B,0,stream>>>(y, y_bf, 2097152);
    cvt_bf16_kernel<<<dim3(2048),B,0,stream>>>(z, z_bf, 2097152);
    graph_softmax_kernel<<<dim3(1024,2),B,0,stream>>>(graph_dec, graph_enc, gdec, genc);
    // decoder stage
    gemm_kernel<<<dim3(64,1,8),B,0,stream>>>(y_bf, wKdt, dec_bk, Kdec,  4096,  64,  512, 0, 64*512, 64, 2, 0);
    gemm_kernel<<<dim3(64,1,8),B,0,stream>>>(y_bf, wVdt, dec_bv, Vtdec, 4096,  64,  512, 0, 64*512, 64, 3, 0);
    if(big){
        gemm_kernel<<<dim3(16,16,32),B,0,stream>>>(Kdec, Kdec, gdec, Sbuf, 1024, 1024, 64, 1024*64, 1024*64, 0, 4, 1);
        attn_sel_pv_kernel<<<dim3(64,32),B,0,stream>>>(Sbuf, Vtdec, gdec, ctx, 1);
    } else {
        attn_kernel<<<dim3(128,32),B,0,stream>>>(Kdec, Kdec, Vtdec, gdec, ctx, 1);
    }
    gemm_big_kernel<64,128,0,0><<<dim3(64,4),B,0,stream>>>(ctx, wOdt, dec_bo, tmp, 4096, 512, 512);
    ln_kernel<<<dim3(4096),B,0,stream>>>(tmp, y, hbuf, h_bf);
    // encoder-decoder stage
    gemm_kernel<<<dim3(64,1,8),B,0,stream>>>(z_bf, wKet, enc_bk, Kenc,  4096,  64,  512, 0, 64*512, 64, 2, 0);
    gemm_kernel<<<dim3(64,1,8),B,0,stream>>>(z_bf, wVet, enc_bv, Vtenc, 4096,  64,  512, 0, 64*512, 64, 3, 0);
    gemm_kernel<<<dim3(64,1,8),B,0,stream>>>(h_bf, wQet, enc_bq, Qenc,  4096,  64,  512, 0, 64*512, 64, 2, 0);
    if(big){
        gemm_kernel<<<dim3(16,16,32),B,0,stream>>>(Qenc, Kenc, genc, Sbuf, 1024, 1024, 64, 1024*64, 1024*64, 0, 4, 0);
        attn_sel_pv_kernel<<<dim3(64,32),B,0,stream>>>(Sbuf, Vtenc, genc, ctx, 0);
    } else {
        attn_kernel<<<dim3(128,32),B,0,stream>>>(Qenc, Kenc, Vtenc, genc, ctx, 0);
    }
    gemm_big_kernel<64,128,0,0><<<dim3(64,4),B,0,stream>>>(ctx, wOet, enc_bo, tmp, 4096, 512, 512);
    ln_kernel<<<dim3(4096),B,0,stream>>>(tmp, hbuf, h2, h2_bf);
    // MLP
    gemm_big_kernel<128,128,1,1><<<dim3(32,16),B,0,stream>>>(h2_bf, wF1t, fc_b1, fc1, 4096, 2048, 512);
    gemm_big_kernel<64,128,0,0><<<dim3(64,4),B,0,stream>>>(fc1, wF2t, fc_b2, tmp, 4096, 512, 2048);
    ln_kernel<<<dim3(4096),B,0,stream>>>(tmp, h2, outp, (short*)0);
}

// Round 7
// 594.417 us; speedup vs baseline: 1.1339x; 1.1339x over previous
//
#include <hip/hip_runtime.h>
#include <stdint.h>

typedef short short8 __attribute__((ext_vector_type(8)));
typedef short short4v __attribute__((ext_vector_type(4)));
typedef float floatx4 __attribute__((ext_vector_type(4)));

#define H_  8
#define NB_ 4      // batch N
#define S_  1024
#define D_  512
#define KD_ 64

__device__ __forceinline__ short f2bf(float f){
    unsigned u = __builtin_bit_cast(unsigned, f);
    u += 0x7fffu + ((u>>16)&1u);
    return (short)(u>>16);
}
__device__ __forceinline__ float wred_addf(float x){
    #pragma unroll
    for(int o=32;o>0;o>>=1) x += __shfl_xor(x,o,64);
    return x;
}
__device__ __forceinline__ float wred_maxf(float x){
    #pragma unroll
    for(int o=32;o>0;o>>=1) x = fmaxf(x,__shfl_xor(x,o,64));
    return x;
}
// monotone 16-bit key for a bf16 pattern; key 0 only from masked entries
__device__ __forceinline__ unsigned bkey(unsigned u){
    return (u & 0x8000u) ? ((~u) & 0xffffu) : (u | 0x8000u);
}
__device__ __forceinline__ float key2f(unsigned k){
    unsigned u = (k & 0x8000u) ? (k & 0x7fffu) : ((~k) & 0xffffu);
    return __builtin_bit_cast(float, u<<16);
}

// ---------------- elementwise fp32 -> bf16 ----------------
__global__ __launch_bounds__(256) void cvt_bf16_kernel(const float* __restrict__ in,
                                                       short* __restrict__ out, int n){
    int i = (blockIdx.x*256 + threadIdx.x)*4;
    if (i + 3 < n){
        floatx4 v = *(const floatx4*)(in + i);
        short4v r;
        #pragma unroll
        for(int j=0;j<4;j++) r[j] = f2bf(v[j]);
        *(short4v*)(out + i) = r;
    }
}

// ---------------- weight transpose + convert: in [R][C] f32 -> out [C][R] bf16 ----------------
__global__ __launch_bounds__(256) void wtrans_kernel(const float* __restrict__ in, short* __restrict__ out,
                                                     int R, int C, long inB, long outB){
    __shared__ float t[32][33];
    int z = blockIdx.z;
    const float* ip = in + (long)z*inB;
    short* op = out + (long)z*outB;
    int c0 = blockIdx.x*32, r0 = blockIdx.y*32;
    int tid = threadIdx.x;
    int r = tid>>3, cq = (tid&7)*4;
    #pragma unroll
    for(int i=0;i<4;i++) t[r][cq+i] = ip[(long)(r0+r)*C + c0+cq+i];
    __syncthreads();
    int c = tid>>3, rq = (tid&7)*4;
    #pragma unroll
    for(int i=0;i<4;i++) op[(long)(c0+c)*R + r0+rq+i] = f2bf(t[rq+i][c]);
}

// ---------------- row softmax of the two graphs -> bf16 ----------------
__global__ __launch_bounds__(256) void graph_softmax_kernel(const float* __restrict__ g0,
                                                            const float* __restrict__ g1,
                                                            short* __restrict__ o0,
                                                            short* __restrict__ o1){
    int row = blockIdx.x;
    const float* g = blockIdx.y ? g1 : g0;
    short* o = blockIdx.y ? o1 : o0;
    const float* gr = g + (long)row*S_;
    short* orow = o + (long)row*S_;
    int tid = threadIdx.x, wave = tid>>6, lane = tid&63;
    __shared__ float red[8];
    float v[4]; float mx = -3.0e38f;
    #pragma unroll
    for(int i=0;i<4;i++){ v[i] = gr[tid + 256*i]; mx = fmaxf(mx, v[i]); }
    mx = wred_maxf(mx);
    if(lane==0) red[wave] = mx;
    __syncthreads();
    mx = fmaxf(fmaxf(red[0],red[1]), fmaxf(red[2],red[3]));
    float s = 0.f;
    #pragma unroll
    for(int i=0;i<4;i++){ v[i] = __expf(v[i]-mx); s += v[i]; }
    s = wred_addf(s);
    if(lane==0) red[4+wave] = s;
    __syncthreads();
    s = red[4]+red[5]+red[6]+red[7];
    float inv = 1.f/s;
    #pragma unroll
    for(int i=0;i<4;i++) orow[tid + 256*i] = f2bf(v[i]*inv);
}

// ---------------- small bf16 MFMA GEMM (direct-global), N=64 projections ----------------
// mode 2: bf16 K/Q layout out[((z*4 + m>>10)*1024 + (m&1023))*64 + n]   (N==64)
// mode 3: bf16 Vt layout  out[((z*4 + m>>10)*64 + n)*1024 + (m&1023)]  (N==64)
__global__ __launch_bounds__(256) void gemm_kernel(
    const short* __restrict__ A, const short* __restrict__ Bt, const float* __restrict__ bias,
    void* __restrict__ out, int M, int N, int K,
    long batchA, long batchB, long batchBias, int mode, int relu)
{
    int z = blockIdx.z;
    const short* Ab = A + (long)z*batchA;
    const short* Bb = Bt + (long)z*batchB;
    const float* bb = bias + (long)z*batchBias;
    int m0 = blockIdx.x*64, n0 = blockIdx.y*64;
    int tid = threadIdx.x, wave = tid>>6, lane = tid&63;
    int quad = lane>>4, nl = lane&15;
    int wm = (wave&1)*32, wn = (wave>>1)*32;
    floatx4 acc[2][2];
    #pragma unroll
    for(int i=0;i<2;i++)
        #pragma unroll
        for(int j=0;j<2;j++) acc[i][j] = (floatx4){0.f,0.f,0.f,0.f};

    const short* Aptr0 = Ab + (long)(m0 + wm + nl)*K + quad*8;
    const short* Aptr1 = Aptr0 + 16*(long)K;
    const short* Bptr0 = Bb + (long)(n0 + wn + nl)*K + quad*8;
    const short* Bptr1 = Bptr0 + 16*(long)K;

    for(int k0=0;k0<K;k0+=32){
        short8 a0 = *(const short8*)(Aptr0 + k0);
        short8 a1 = *(const short8*)(Aptr1 + k0);
        short8 b0 = *(const short8*)(Bptr0 + k0);
        short8 b1 = *(const short8*)(Bptr1 + k0);
        acc[0][0] = __builtin_amdgcn_mfma_f32_16x16x32_bf16(a0,b0,acc[0][0],0,0,0);
        acc[0][1] = __builtin_amdgcn_mfma_f32_16x16x32_bf16(a0,b1,acc[0][1],0,0,0);
        acc[1][0] = __builtin_amdgcn_mfma_f32_16x16x32_bf16(a1,b0,acc[1][0],0,0,0);
        acc[1][1] = __builtin_amdgcn_mfma_f32_16x16x32_bf16(a1,b1,acc[1][1],0,0,0);
    }
    #pragma unroll
    for(int i=0;i<2;i++){
        #pragma unroll
        for(int j=0;j<2;j++){
            int n = n0 + wn + j*16 + nl;
            float bv = bb[n];
            #pragma unroll
            for(int r=0;r<4;r++){
                int m = m0 + wm + i*16 + quad*4 + r;
                float v = acc[i][j][r] + bv;
                if(relu) v = fmaxf(v, 0.f);
                if(mode==0)      ((float*)out)[(long)m*N + n] = v;
                else if(mode==1) ((short*)out)[(long)m*N + n] = f2bf(v);
                else if(mode==2) ((short*)out)[ ((long)(z*NB_ + (m>>10))*S_ + (m&1023))*KD_ + n ] = f2bf(v);
                else             ((short*)out)[ ((long)(z*NB_ + (m>>10))*KD_ + n)*S_ + (m&1023) ] = f2bf(v);
            }
        }
    }
}

// ---------------- big MFMA GEMM, m97 pattern ----------------
template<int TM, int TN, int OUTBF, int RELU>
__global__ __launch_bounds__(256) void gemm_big_kernel(
    const short* __restrict__ A, const short* __restrict__ Bt, const float* __restrict__ bias,
    void* __restrict__ out, int M, int N, int K)
{
    __shared__ short As[TM*32];
    __shared__ short Bs[TN*32];
    int m0 = blockIdx.x*TM, n0 = blockIdx.y*TN;
    int tid = threadIdx.x, wave = tid>>6, lane = tid&63, quad = lane>>4, nl = lane&15;
    constexpr int MI = TM/32, NI = TN/32;
    int wm = (wave&1)*(TM/2), wn = (wave>>1)*(TN/2);
    floatx4 acc[MI][NI];
    #pragma unroll
    for(int i=0;i<MI;i++)
        #pragma unroll
        for(int j=0;j<NI;j++) acc[i][j] = (floatx4){0.f,0.f,0.f,0.f};

    int r = tid>>2, c = (tid&3)*8;
    for(int k0=0;k0<K;k0+=32){
        __syncthreads();
        #pragma unroll
        for(int i=0;i<TM/64;i++)
            __builtin_amdgcn_global_load_lds(
                (const __attribute__((address_space(1))) unsigned*)(A + (long)(m0 + r + i*64)*K + k0 + c),
                (__attribute__((address_space(3))) unsigned*)((char*)As + i*4096 + wave*1024),
                16, 0, 0);
        #pragma unroll
        for(int i=0;i<TN/64;i++)
            __builtin_amdgcn_global_load_lds(
                (const __attribute__((address_space(1))) unsigned*)(Bt + (long)(n0 + r + i*64)*K + k0 + c),
                (__attribute__((address_space(3))) unsigned*)((char*)Bs + i*4096 + wave*1024),
                16, 0, 0);
        __syncthreads();
        short8 af[MI], bfr[NI];
        #pragma unroll
        for(int i=0;i<MI;i++) af[i] = *(const short8*)(As + (wm + i*16 + nl)*32 + quad*8);
        #pragma unroll
        for(int j=0;j<NI;j++) bfr[j] = *(const short8*)(Bs + (wn + j*16 + nl)*32 + quad*8);
        #pragma unroll
        for(int i=0;i<MI;i++)
            #pragma unroll
            for(int j=0;j<NI;j++)
                acc[i][j] = __builtin_amdgcn_mfma_f32_16x16x32_bf16(af[i],bfr[j],acc[i][j],0,0,0);
    }
    #pragma unroll
    for(int j=0;j<NI;j++){
        int n = n0 + wn + j*16 + nl;
        float bv = bias[n];
        #pragma unroll
        for(int i=0;i<MI;i++){
            #pragma unroll
            for(int rr=0;rr<4;rr++){
                int m = m0 + wm + i*16 + quad*4 + rr;
                float v = acc[i][j][rr] + bv;
                if(RELU) v = fmaxf(v, 0.f);
                if(OUTBF) ((short*)out)[(long)m*N + n] = f2bf(v);
                else      ((float*)out)[(long)m*N + n] = v;
            }
        }
    }
}

// ---------------- fused attention v3: 8 q-rows/block, 16 KiB LDS ----------------
// Qb/Kb: bf16 [HN][S][64]; Vt: bf16 [HN][64][S]; graph: softmaxed bf16 [S][S]
// Phase 1: QK^T/8 -> bf16 scores in LDS (row rot 8q). Phase 2: per-wave 2 rows as two
// independent 32-lane groups; 16-bit-key exact bisection, fixed 16 iters, one 5-deep
// shuffle chain per iter serves both rows. Phase 3: PV MFMA (rows duplicated nl&7).
__global__ __launch_bounds__(256) void attn_kernel(
    const short* __restrict__ Qb, const short* __restrict__ Kb, const short* __restrict__ Vt,
    const short* __restrict__ graph, short* __restrict__ ctx, int causal)
{
    __shared__ short attb[8*1024];   // 16 KiB
    int qt = blockIdx.x, hn = blockIdx.y;
    int h = hn>>2, n = hn&3;
    int q0 = qt*8;
    int tid=threadIdx.x, wave=tid>>6, lane=tid&63, quad=lane>>4, nl=lane&15;

    // ---- phase 1: scores -> bf16 LDS (rot 8q) ----
    const short* Qp = Qb + ((long)hn*S_ + q0 + (nl&7))*KD_ + quad*8;
    short8 aq0 = *(const short8*)(Qp);
    short8 aq1 = *(const short8*)(Qp + 32);
    const short* Kp = Kb + (long)hn*S_*KD_;
    int stmax = causal ? ((q0+7)>>4) : 63;
    for(int st=wave; st<=stmax; st+=4){
        const short* kp = Kp + (st*16 + nl)*KD_ + quad*8;
        short8 b0 = *(const short8*)(kp);
        short8 b1 = *(const short8*)(kp + 32);
        floatx4 cc = (floatx4){0.f,0.f,0.f,0.f};
        cc = __builtin_amdgcn_mfma_f32_16x16x32_bf16(aq0,b0,cc,0,0,0);
        cc = __builtin_amdgcn_mfma_f32_16x16x32_bf16(aq1,b1,cc,0,0,0);
        #pragma unroll
        for(int rr=0;rr<4;rr++){
            int q = quad*4 + rr, s = st*16 + nl;
            if(q < 8) attb[q*1024 + ((s + 8*q)&1023)] = f2bf(cc[rr]*0.125f);
        }
    }
    __syncthreads();

    // ---- phase 2: selection + softmax + blend (2 rows/wave via 32-lane groups) ----
    {
        int g = lane>>5, li = lane&31;
        int q = wave*2 + g;
        int qg = q0 + q;
        int slimit = causal ? qg : 1023;
        short* rowp = attb + q*1024;
        unsigned mv[32];
        unsigned mk = 0u;
        #pragma unroll
        for(int t=0;t<2;t++){
            int sb = li*16 + t*512;
            int p0 = (sb + 8*q) & 1023;
            short8 c0 = *(const short8*)(rowp + p0);
            short8 c1 = *(const short8*)(rowp + ((p0+8)&1023));
            #pragma unroll
            for(int j=0;j<8;j++){
                unsigned k0 = (sb+j   <= slimit) ? bkey((unsigned)(unsigned short)c0[j]) : 0u;
                unsigned k1 = (sb+8+j <= slimit) ? bkey((unsigned)(unsigned short)c1[j]) : 0u;
                mv[t*16+j]   = k0; mk = k0>mk?k0:mk;
                mv[t*16+8+j] = k1; mk = k1>mk?k1:mk;
            }
        }
        // group max (5-deep, stays within 32-lane group)
        #pragma unroll
        for(int o=1;o<=16;o<<=1){ unsigned tt=__shfl_xor(mk,o,64); mk = tt>mk?tt:mk; }
        unsigned lo=0u, hi=mk+1u;
        // exact bisection: 16 fixed iterations (converged state is self-stable)
        for(int it=0; it<16; ++it){
            unsigned mid = lo + ((hi-lo)>>1);
            unsigned cnt = 0u;
            #pragma unroll
            for(int j=0;j<32;j++) cnt += (mv[j] >= mid) ? 1u : 0u;
            #pragma unroll
            for(int o=1;o<=16;o<<=1) cnt += __shfl_xor(cnt,o,64);
            if(cnt >= 128u){ lo = mid; if(cnt == 128u) hi = mid+1u; }
            else hi = mid;
        }
        // exp + sum (stash exp back into mv)
        float mxf = key2f(mk);
        float sm = 0.f;
        #pragma unroll
        for(int j=0;j<32;j++){
            unsigned k = mv[j];
            float e = (k >= lo && k != 0u) ? __expf(key2f(k)-mxf) : 0.f;
            mv[j] = __builtin_bit_cast(unsigned, e);
            sm += e;
        }
        #pragma unroll
        for(int o=1;o<=16;o<<=1) sm += __shfl_xor(sm,o,64);
        float inv = 0.5f/sm;   // (1-gw)=0.5
        const short* grow = graph + (long)qg*1024;
        #pragma unroll
        for(int t=0;t<2;t++){
            int sb = li*16 + t*512;
            short8 g0 = *(const short8*)(grow + sb);
            short8 g1 = *(const short8*)(grow + sb + 8);
            short8 o0, o1;
            #pragma unroll
            for(int j=0;j<8;j++){
                float gv0 = __builtin_bit_cast(float, ((unsigned)(unsigned short)g0[j])<<16);
                float gv1 = __builtin_bit_cast(float, ((unsigned)(unsigned short)g1[j])<<16);
                float e0 = __builtin_bit_cast(float, mv[t*16+j]);
                float e1 = __builtin_bit_cast(float, mv[t*16+8+j]);
                o0[j] = f2bf(0.5f*gv0 + e0*inv);
                o1[j] = f2bf(0.5f*gv1 + e1*inv);
            }
            int p0 = (sb + 8*q) & 1023;
            *(short8*)(rowp + p0) = o0;
            *(short8*)(rowp + ((p0+8)&1023)) = o1;
        }
    }
    __syncthreads();

    // ---- phase 3: ctx = att @ V (rows duplicated nl&7, writes guarded) ----
    int v0 = wave*16;
    const short* Vp = Vt + ((long)hn*KD_ + v0 + nl)*S_;
    floatx4 o4 = (floatx4){0.f,0.f,0.f,0.f};
    int arow = nl & 7;
    for(int s0=0; s0<1024; s0+=32){
        int cs = (s0 + quad*8 + 8*arow) & 1023;
        short8 ap = *(const short8*)(attb + arow*1024 + cs);
        short8 bv = *(const short8*)(Vp + s0 + quad*8);
        o4 = __builtin_amdgcn_mfma_f32_16x16x32_bf16(ap,bv,o4,0,0,0);
    }
    #pragma unroll
    for(int rr=0;rr<4;rr++){
        int q = quad*4 + rr;
        if(q < 8)
            ctx[ ((long)(n*S_ + q0 + q))*512 + h*KD_ + v0 + nl ] = f2bf(o4[rr]);
    }
}

// ---------------- LayerNorm(x + res) ----------------
__global__ __launch_bounds__(256) void ln_kernel(const float* __restrict__ x, const float* __restrict__ res,
                                                 float* __restrict__ outf, short* __restrict__ outb){
    long row = blockIdx.x;
    const float* xr = x + row*D_;
    const float* rr = res + row*D_;
    int tid = threadIdx.x, wave = tid>>6, lane = tid&63;
    float t0 = xr[tid] + rr[tid];
    float t1 = xr[tid+256] + rr[tid+256];
    float s = t0 + t1, s2 = t0*t0 + t1*t1;
    __shared__ float red[8];
    s = wred_addf(s); s2 = wred_addf(s2);
    if(lane==0){ red[wave] = s; red[4+wave] = s2; }
    __syncthreads();
    s  = red[0]+red[1]+red[2]+red[3];
    s2 = red[4]+red[5]+red[6]+red[7];
    float mean = s*(1.f/512.f);
    float var = s2*(1.f/512.f) - mean*mean;
    float rs = rsqrtf(var + 1e-5f);
    float o0 = (t0-mean)*rs, o1 = (t1-mean)*rs;
    if(outf){ outf[row*D_+tid] = o0; outf[row*D_+tid+256] = o1; }
    if(outb){ outb[row*D_+tid] = f2bf(o0); outb[row*D_+tid+256] = f2bf(o1); }
}

extern "C" void kernel_launch(void* const* d_in, const int* in_sizes, int n_in,
                              void* d_out, int out_size, void* d_ws, size_t ws_size,
                              hipStream_t stream)
{
    const float* z         = (const float*)d_in[0];
    const float* y         = (const float*)d_in[1];
    const float* graph_dec = (const float*)d_in[2];
    const float* graph_enc = (const float*)d_in[3];
    const float* dec_Wk = (const float*)d_in[4];  const float* dec_bk = (const float*)d_in[5];
    const float* dec_Wv = (const float*)d_in[6];  const float* dec_bv = (const float*)d_in[7];
    const float* dec_Wo = (const float*)d_in[8];  const float* dec_bo = (const float*)d_in[9];
    const float* enc_Wk = (const float*)d_in[10]; const float* enc_bk = (const float*)d_in[11];
    const float* enc_Wq = (const float*)d_in[12]; const float* enc_bq = (const float*)d_in[13];
    const float* enc_Wv = (const float*)d_in[14]; const float* enc_bv = (const float*)d_in[15];
    const float* enc_Wo = (const float*)d_in[16]; const float* enc_bo = (const float*)d_in[17];
    const float* fc_W1  = (const float*)d_in[18]; const float* fc_b1  = (const float*)d_in[19];
    const float* fc_W2  = (const float*)d_in[20]; const float* fc_b2  = (const float*)d_in[21];

    char* ws = (char*)d_ws;
    short* gdec  = (short*)(ws + 0x0000000);
    short* genc  = (short*)(ws + 0x0400000);
    short* y_bf  = (short*)(ws + 0x0800000);
    short* z_bf  = (short*)(ws + 0x0C00000);
    short* Kdec  = (short*)(ws + 0x1000000);
    short* Vtdec = (short*)(ws + 0x1400000);
    short* Kenc  = (short*)(ws + 0x1800000);
    short* Vtenc = (short*)(ws + 0x1C00000);
    short* Qenc  = (short*)(ws + 0x2000000);
    short* ctx   = (short*)(ws + 0x2400000);
    float* tmp   = (float*)(ws + 0x2800000);
    float* hbuf  = (float*)(ws + 0x3000000);
    short* h_bf  = (short*)(ws + 0x3800000);
    float* h2    = (float*)(ws + 0x3C00000);
    short* h2_bf = (short*)(ws + 0x4400000);
    short* fc1   = (short*)(ws + 0x4800000);
    short* wKdt  = (short*)(ws + 0x5800000);
    short* wVdt  = (short*)(ws + 0x5880000);
    short* wOdt  = (short*)(ws + 0x5900000);
    short* wKet  = (short*)(ws + 0x5980000);
    short* wQet  = (short*)(ws + 0x5A00000);
    short* wVet  = (short*)(ws + 0x5A80000);
    short* wOet  = (short*)(ws + 0x5B00000);
    short* wF1t  = (short*)(ws + 0x5B80000);
    short* wF2t  = (short*)(ws + 0x5D80000);
    float* outp  = (float*)d_out;

    dim3 B(256);
    // weight transposes -> bf16 [N][K]
    wtrans_kernel<<<dim3(2,16,8),  B,0,stream>>>(dec_Wk, wKdt, 512,  64, 512*64, 64*512);
    wtrans_kernel<<<dim3(2,16,8),  B,0,stream>>>(dec_Wv, wVdt, 512,  64, 512*64, 64*512);
    wtrans_kernel<<<dim3(16,16,1), B,0,stream>>>(dec_Wo, wOdt, 512, 512, 0, 0);
    wtrans_kernel<<<dim3(2,16,8),  B,0,stream>>>(enc_Wk, wKet, 512,  64, 512*64, 64*512);
    wtrans_kernel<<<dim3(2,16,8),  B,0,stream>>>(enc_Wq, wQet, 512,  64, 512*64, 64*512);
    wtrans_kernel<<<dim3(2,16,8),  B,0,stream>>>(enc_Wv, wVet, 512,  64, 512*64, 64*512);
    wtrans_kernel<<<dim3(16,16,1), B,0,stream>>>(enc_Wo, wOet, 512, 512, 0, 0);
    wtrans_kernel<<<dim3(64,16,1), B,0,stream>>>(fc_W1,  wF1t, 512,2048, 0, 0);
    wtrans_kernel<<<dim3(16,64,1), B,0,stream>>>(fc_W2,  wF2t,2048, 512, 0, 0);
    cvt_bf16_kernel<<<dim3(2048),B,0,stream>>>(y, y_bf, 2097152);
    cvt_bf16_kernel<<<dim3(2048),B,0,stream>>>(z, z_bf, 2097152);
    graph_softmax_kernel<<<dim3(1024,2),B,0,stream>>>(graph_dec, graph_enc, gdec, genc);
    // decoder stage
    gemm_kernel<<<dim3(64,1,8),B,0,stream>>>(y_bf, wKdt, dec_bk, Kdec,  4096,  64,  512, 0, 64*512, 64, 2, 0);
    gemm_kernel<<<dim3(64,1,8),B,0,stream>>>(y_bf, wVdt, dec_bv, Vtdec, 4096,  64,  512, 0, 64*512, 64, 3, 0);
    attn_kernel<<<dim3(128,32),B,0,stream>>>(Kdec, Kdec, Vtdec, gdec, ctx, 1);
    gemm_big_kernel<64,128,0,0><<<dim3(64,4),B,0,stream>>>(ctx, wOdt, dec_bo, tmp, 4096, 512, 512);
    ln_kernel<<<dim3(4096),B,0,stream>>>(tmp, y, hbuf, h_bf);
    // encoder-decoder stage
    gemm_kernel<<<dim3(64,1,8),B,0,stream>>>(z_bf, wKet, enc_bk, Kenc,  4096,  64,  512, 0, 64*512, 64, 2, 0);
    gemm_kernel<<<dim3(64,1,8),B,0,stream>>>(z_bf, wVet, enc_bv, Vtenc, 4096,  64,  512, 0, 64*512, 64, 3, 0);
    gemm_kernel<<<dim3(64,1,8),B,0,stream>>>(h_bf, wQet, enc_bq, Qenc,  4096,  64,  512, 0, 64*512, 64, 2, 0);
    attn_kernel<<<dim3(128,32),B,0,stream>>>(Qenc, Kenc, Vtenc, genc, ctx, 0);
    gemm_big_kernel<64,128,0,0><<<dim3(64,4),B,0,stream>>>(ctx, wOet, enc_bo, tmp, 4096, 512, 512);
    ln_kernel<<<dim3(4096),B,0,stream>>>(tmp, hbuf, h2, h2_bf);
    // MLP
    gemm_big_kernel<128,128,1,1><<<dim3(32,16),B,0,stream>>>(h2_bf, wF1t, fc_b1, fc1, 4096, 2048, 512);
    gemm_big_kernel<64,128,0,0><<<dim3(64,4),B,0,stream>>>(fc1, wF2t, fc_b2, tmp, 4096, 512, 2048);
    ln_kernel<<<dim3(4096),B,0,stream>>>(tmp, h2, outp, (short*)0);
}

// Round 8
// 588.793 us; speedup vs baseline: 1.1447x; 1.0096x over previous
//
#include <hip/hip_runtime.h>
#include <stdint.h>

typedef short short8 __attribute__((ext_vector_type(8)));
typedef short short4v __attribute__((ext_vector_type(4)));
typedef float floatx4 __attribute__((ext_vector_type(4)));

#define H_  8
#define NB_ 4      // batch N
#define S_  1024
#define D_  512
#define KD_ 64

__device__ __forceinline__ short f2bf(float f){
    unsigned u = __builtin_bit_cast(unsigned, f);
    u += 0x7fffu + ((u>>16)&1u);
    return (short)(u>>16);
}
__device__ __forceinline__ float wred_addf(float x){
    #pragma unroll
    for(int o=32;o>0;o>>=1) x += __shfl_xor(x,o,64);
    return x;
}
__device__ __forceinline__ float wred_maxf(float x){
    #pragma unroll
    for(int o=32;o>0;o>>=1) x = fmaxf(x,__shfl_xor(x,o,64));
    return x;
}
// monotone 16-bit key for a bf16 pattern; key 0 only from masked entries
__device__ __forceinline__ unsigned bkey(unsigned u){
    return (u & 0x8000u) ? ((~u) & 0xffffu) : (u | 0x8000u);
}
__device__ __forceinline__ float key2f(unsigned k){
    unsigned u = (k & 0x8000u) ? (k & 0x7fffu) : ((~k) & 0xffffu);
    return __builtin_bit_cast(float, u<<16);
}

// ---------------- elementwise fp32 -> bf16 ----------------
__global__ __launch_bounds__(256) void cvt_bf16_kernel(const float* __restrict__ in,
                                                       short* __restrict__ out, int n){
    int i = (blockIdx.x*256 + threadIdx.x)*4;
    if (i + 3 < n){
        floatx4 v = *(const floatx4*)(in + i);
        short4v r;
        #pragma unroll
        for(int j=0;j<4;j++) r[j] = f2bf(v[j]);
        *(short4v*)(out + i) = r;
    }
}

// ---------------- weight transpose + convert: in [R][C] f32 -> out [C][R] bf16 ----------------
__global__ __launch_bounds__(256) void wtrans_kernel(const float* __restrict__ in, short* __restrict__ out,
                                                     int R, int C, long inB, long outB){
    __shared__ float t[32][33];
    int z = blockIdx.z;
    const float* ip = in + (long)z*inB;
    short* op = out + (long)z*outB;
    int c0 = blockIdx.x*32, r0 = blockIdx.y*32;
    int tid = threadIdx.x;
    int r = tid>>3, cq = (tid&7)*4;
    #pragma unroll
    for(int i=0;i<4;i++) t[r][cq+i] = ip[(long)(r0+r)*C + c0+cq+i];
    __syncthreads();
    int c = tid>>3, rq = (tid&7)*4;
    #pragma unroll
    for(int i=0;i<4;i++) op[(long)(c0+c)*R + r0+rq+i] = f2bf(t[rq+i][c]);
}

// ---------------- row softmax of the two graphs -> bf16 ----------------
__global__ __launch_bounds__(256) void graph_softmax_kernel(const float* __restrict__ g0,
                                                            const float* __restrict__ g1,
                                                            short* __restrict__ o0,
                                                            short* __restrict__ o1){
    int row = blockIdx.x;
    const float* g = blockIdx.y ? g1 : g0;
    short* o = blockIdx.y ? o1 : o0;
    const float* gr = g + (long)row*S_;
    short* orow = o + (long)row*S_;
    int tid = threadIdx.x, wave = tid>>6, lane = tid&63;
    __shared__ float red[8];
    float v[4]; float mx = -3.0e38f;
    #pragma unroll
    for(int i=0;i<4;i++){ v[i] = gr[tid + 256*i]; mx = fmaxf(mx, v[i]); }
    mx = wred_maxf(mx);
    if(lane==0) red[wave] = mx;
    __syncthreads();
    mx = fmaxf(fmaxf(red[0],red[1]), fmaxf(red[2],red[3]));
    float s = 0.f;
    #pragma unroll
    for(int i=0;i<4;i++){ v[i] = __expf(v[i]-mx); s += v[i]; }
    s = wred_addf(s);
    if(lane==0) red[4+wave] = s;
    __syncthreads();
    s = red[4]+red[5]+red[6]+red[7];
    float inv = 1.f/s;
    #pragma unroll
    for(int i=0;i<4;i++) orow[tid + 256*i] = f2bf(v[i]*inv);
}

// ---------------- small bf16 MFMA GEMM (direct-global), N=64 projections ----------------
// mode 2: bf16 K/Q layout out[((z*4 + m>>10)*1024 + (m&1023))*64 + n]   (N==64)
// mode 3: bf16 Vt layout  out[((z*4 + m>>10)*64 + n)*1024 + (m&1023)]  (N==64)
__global__ __launch_bounds__(256) void gemm_kernel(
    const short* __restrict__ A, const short* __restrict__ Bt, const float* __restrict__ bias,
    void* __restrict__ out, int M, int N, int K,
    long batchA, long batchB, long batchBias, int mode, int relu)
{
    int z = blockIdx.z;
    const short* Ab = A + (long)z*batchA;
    const short* Bb = Bt + (long)z*batchB;
    const float* bb = bias + (long)z*batchBias;
    int m0 = blockIdx.x*64, n0 = blockIdx.y*64;
    int tid = threadIdx.x, wave = tid>>6, lane = tid&63;
    int quad = lane>>4, nl = lane&15;
    int wm = (wave&1)*32, wn = (wave>>1)*32;
    floatx4 acc[2][2];
    #pragma unroll
    for(int i=0;i<2;i++)
        #pragma unroll
        for(int j=0;j<2;j++) acc[i][j] = (floatx4){0.f,0.f,0.f,0.f};

    const short* Aptr0 = Ab + (long)(m0 + wm + nl)*K + quad*8;
    const short* Aptr1 = Aptr0 + 16*(long)K;
    const short* Bptr0 = Bb + (long)(n0 + wn + nl)*K + quad*8;
    const short* Bptr1 = Bptr0 + 16*(long)K;

    for(int k0=0;k0<K;k0+=32){
        short8 a0 = *(const short8*)(Aptr0 + k0);
        short8 a1 = *(const short8*)(Aptr1 + k0);
        short8 b0 = *(const short8*)(Bptr0 + k0);
        short8 b1 = *(const short8*)(Bptr1 + k0);
        acc[0][0] = __builtin_amdgcn_mfma_f32_16x16x32_bf16(a0,b0,acc[0][0],0,0,0);
        acc[0][1] = __builtin_amdgcn_mfma_f32_16x16x32_bf16(a0,b1,acc[0][1],0,0,0);
        acc[1][0] = __builtin_amdgcn_mfma_f32_16x16x32_bf16(a1,b0,acc[1][0],0,0,0);
        acc[1][1] = __builtin_amdgcn_mfma_f32_16x16x32_bf16(a1,b1,acc[1][1],0,0,0);
    }
    #pragma unroll
    for(int i=0;i<2;i++){
        #pragma unroll
        for(int j=0;j<2;j++){
            int n = n0 + wn + j*16 + nl;
            float bv = bb[n];
            #pragma unroll
            for(int r=0;r<4;r++){
                int m = m0 + wm + i*16 + quad*4 + r;
                float v = acc[i][j][r] + bv;
                if(relu) v = fmaxf(v, 0.f);
                if(mode==0)      ((float*)out)[(long)m*N + n] = v;
                else if(mode==1) ((short*)out)[(long)m*N + n] = f2bf(v);
                else if(mode==2) ((short*)out)[ ((long)(z*NB_ + (m>>10))*S_ + (m&1023))*KD_ + n ] = f2bf(v);
                else             ((short*)out)[ ((long)(z*NB_ + (m>>10))*KD_ + n)*S_ + (m&1023) ] = f2bf(v);
            }
        }
    }
}

// ---------------- big MFMA GEMM, m97 pattern ----------------
template<int TM, int TN, int OUTBF, int RELU>
__global__ __launch_bounds__(256) void gemm_big_kernel(
    const short* __restrict__ A, const short* __restrict__ Bt, const float* __restrict__ bias,
    void* __restrict__ out, int M, int N, int K)
{
    __shared__ short As[TM*32];
    __shared__ short Bs[TN*32];
    int m0 = blockIdx.x*TM, n0 = blockIdx.y*TN;
    int tid = threadIdx.x, wave = tid>>6, lane = tid&63, quad = lane>>4, nl = lane&15;
    constexpr int MI = TM/32, NI = TN/32;
    int wm = (wave&1)*(TM/2), wn = (wave>>1)*(TN/2);
    floatx4 acc[MI][NI];
    #pragma unroll
    for(int i=0;i<MI;i++)
        #pragma unroll
        for(int j=0;j<NI;j++) acc[i][j] = (floatx4){0.f,0.f,0.f,0.f};

    int r = tid>>2, c = (tid&3)*8;
    for(int k0=0;k0<K;k0+=32){
        __syncthreads();
        #pragma unroll
        for(int i=0;i<TM/64;i++)
            __builtin_amdgcn_global_load_lds(
                (const __attribute__((address_space(1))) unsigned*)(A + (long)(m0 + r + i*64)*K + k0 + c),
                (__attribute__((address_space(3))) unsigned*)((char*)As + i*4096 + wave*1024),
                16, 0, 0);
        #pragma unroll
        for(int i=0;i<TN/64;i++)
            __builtin_amdgcn_global_load_lds(
                (const __attribute__((address_space(1))) unsigned*)(Bt + (long)(n0 + r + i*64)*K + k0 + c),
                (__attribute__((address_space(3))) unsigned*)((char*)Bs + i*4096 + wave*1024),
                16, 0, 0);
        __syncthreads();
        short8 af[MI], bfr[NI];
        #pragma unroll
        for(int i=0;i<MI;i++) af[i] = *(const short8*)(As + (wm + i*16 + nl)*32 + quad*8);
        #pragma unroll
        for(int j=0;j<NI;j++) bfr[j] = *(const short8*)(Bs + (wn + j*16 + nl)*32 + quad*8);
        #pragma unroll
        for(int i=0;i<MI;i++)
            #pragma unroll
            for(int j=0;j<NI;j++)
                acc[i][j] = __builtin_amdgcn_mfma_f32_16x16x32_bf16(af[i],bfr[j],acc[i][j],0,0,0);
    }
    #pragma unroll
    for(int j=0;j<NI;j++){
        int n = n0 + wn + j*16 + nl;
        float bv = bias[n];
        #pragma unroll
        for(int i=0;i<MI;i++){
            #pragma unroll
            for(int rr=0;rr<4;rr++){
                int m = m0 + wm + i*16 + quad*4 + rr;
                float v = acc[i][j][rr] + bv;
                if(RELU) v = fmaxf(v, 0.f);
                if(OUTBF) ((short*)out)[(long)m*N + n] = f2bf(v);
                else      ((float*)out)[(long)m*N + n] = v;
            }
        }
    }
}

// ---------------- fused attention v4: 8 q-rows/block, 16 KiB LDS, register-pinned keys ----------------
// Qb/Kb: bf16 [HN][S][64]; Vt: bf16 [HN][64][S]; graph: softmaxed bf16 [S][S]
__global__ __launch_bounds__(256,4) void attn_kernel(
    const short* __restrict__ Qb, const short* __restrict__ Kb, const short* __restrict__ Vt,
    const short* __restrict__ graph, short* __restrict__ ctx, int causal)
{
    __shared__ short attb[8*1024];   // 16 KiB
    int qt = blockIdx.x, hn = blockIdx.y;
    int h = hn>>2, n = hn&3;
    int q0 = qt*8;
    int tid=threadIdx.x, wave=tid>>6, lane=tid&63, quad=lane>>4, nl=lane&15;

    // ---- phase 1: scores -> bf16 LDS (rot 8q) ----
    const short* Qp = Qb + ((long)hn*S_ + q0 + (nl&7))*KD_ + quad*8;
    short8 aq0 = *(const short8*)(Qp);
    short8 aq1 = *(const short8*)(Qp + 32);
    const short* Kp = Kb + (long)hn*S_*KD_;
    int stmax = causal ? ((q0+7)>>4) : 63;
    for(int st=wave; st<=stmax; st+=4){
        const short* kp = Kp + (st*16 + nl)*KD_ + quad*8;
        short8 b0 = *(const short8*)(kp);
        short8 b1 = *(const short8*)(kp + 32);
        floatx4 cc = (floatx4){0.f,0.f,0.f,0.f};
        cc = __builtin_amdgcn_mfma_f32_16x16x32_bf16(aq0,b0,cc,0,0,0);
        cc = __builtin_amdgcn_mfma_f32_16x16x32_bf16(aq1,b1,cc,0,0,0);
        #pragma unroll
        for(int rr=0;rr<4;rr++){
            int q = quad*4 + rr, s = st*16 + nl;
            if(q < 8) attb[q*1024 + ((s + 8*q)&1023)] = f2bf(cc[rr]*0.125f);
        }
    }
    __syncthreads();

    // ---- phase 2: selection + softmax + blend (2 rows/wave via 32-lane groups) ----
    {
        int g = lane>>5, li = lane&31;
        int q = wave*2 + g;
        int qg = q0 + q;
        int slimit = causal ? qg : 1023;
        short* rowp = attb + q*1024;
        unsigned mv[32];
        unsigned mk = 0u;
        #pragma unroll
        for(int t=0;t<2;t++){
            int sb = li*16 + t*512;
            int p0 = (sb + 8*q) & 1023;
            short8 c0 = *(const short8*)(rowp + p0);
            short8 c1 = *(const short8*)(rowp + ((p0+8)&1023));
            #pragma unroll
            for(int j=0;j<8;j++){
                unsigned k0 = (sb+j   <= slimit) ? bkey((unsigned)(unsigned short)c0[j]) : 0u;
                unsigned k1 = (sb+8+j <= slimit) ? bkey((unsigned)(unsigned short)c1[j]) : 0u;
                mv[t*16+j]   = k0; mk = k0>mk?k0:mk;
                mv[t*16+8+j] = k1; mk = k1>mk?k1:mk;
            }
        }
        // pin keys into architectural VGPRs; values become opaque -> no rematerialization
        #pragma unroll
        for(int j=0;j<32;j++) asm volatile("" : "+v"(mv[j]));
        // group max (5-deep, stays within 32-lane group)
        #pragma unroll
        for(int o=1;o<=16;o<<=1){ unsigned tt=__shfl_xor(mk,o,64); mk = tt>mk?tt:mk; }
        unsigned lo=0u, hi=mk+1u;
        // exact bisection: 16 fixed iterations, branchless updates
        for(int it=0; it<16; ++it){
            unsigned mid = lo + ((hi-lo)>>1);
            unsigned cnt = 0u;
            #pragma unroll
            for(int j=0;j<32;j++) cnt += (mv[j] >= mid) ? 1u : 0u;
            #pragma unroll
            for(int o=1;o<=16;o<<=1) cnt += __shfl_xor(cnt,o,64);
            bool ge = (cnt >= 128u);
            bool eq = (cnt == 128u);
            lo = ge ? mid : lo;
            hi = ge ? (eq ? mid+1u : hi) : mid;
        }
        // exp + sum (stash exp back into mv)
        float mxf = key2f(mk);
        float sm = 0.f;
        #pragma unroll
        for(int j=0;j<32;j++){
            unsigned k = mv[j];
            float e = (k >= lo && k != 0u) ? __expf(key2f(k)-mxf) : 0.f;
            mv[j] = __builtin_bit_cast(unsigned, e);
            sm += e;
        }
        #pragma unroll
        for(int o=1;o<=16;o<<=1) sm += __shfl_xor(sm,o,64);
        float inv = 0.5f/sm;   // (1-gw)=0.5
        const short* grow = graph + (long)qg*1024;
        #pragma unroll
        for(int t=0;t<2;t++){
            int sb = li*16 + t*512;
            short8 g0 = *(const short8*)(grow + sb);
            short8 g1 = *(const short8*)(grow + sb + 8);
            short8 o0, o1;
            #pragma unroll
            for(int j=0;j<8;j++){
                float gv0 = __builtin_bit_cast(float, ((unsigned)(unsigned short)g0[j])<<16);
                float gv1 = __builtin_bit_cast(float, ((unsigned)(unsigned short)g1[j])<<16);
                float e0 = __builtin_bit_cast(float, mv[t*16+j]);
                float e1 = __builtin_bit_cast(float, mv[t*16+8+j]);
                o0[j] = f2bf(0.5f*gv0 + e0*inv);
                o1[j] = f2bf(0.5f*gv1 + e1*inv);
            }
            int p0 = (sb + 8*q) & 1023;
            *(short8*)(rowp + p0) = o0;
            *(short8*)(rowp + ((p0+8)&1023)) = o1;
        }
    }
    __syncthreads();

    // ---- phase 3: ctx = att @ V (rows duplicated nl&7, writes guarded) ----
    int v0 = wave*16;
    const short* Vp = Vt + ((long)hn*KD_ + v0 + nl)*S_;
    floatx4 o4 = (floatx4){0.f,0.f,0.f,0.f};
    int arow = nl & 7;
    for(int s0=0; s0<1024; s0+=32){
        int cs = (s0 + quad*8 + 8*arow) & 1023;
        short8 ap = *(const short8*)(attb + arow*1024 + cs);
        short8 bv = *(const short8*)(Vp + s0 + quad*8);
        o4 = __builtin_amdgcn_mfma_f32_16x16x32_bf16(ap,bv,o4,0,0,0);
    }
    #pragma unroll
    for(int rr=0;rr<4;rr++){
        int q = quad*4 + rr;
        if(q < 8)
            ctx[ ((long)(n*S_ + q0 + q))*512 + h*KD_ + v0 + nl ] = f2bf(o4[rr]);
    }
}

// ---------------- LayerNorm(x + res) ----------------
__global__ __launch_bounds__(256) void ln_kernel(const float* __restrict__ x, const float* __restrict__ res,
                                                 float* __restrict__ outf, short* __restrict__ outb){
    long row = blockIdx.x;
    const float* xr = x + row*D_;
    const float* rr = res + row*D_;
    int tid = threadIdx.x, wave = tid>>6, lane = tid&63;
    float t0 = xr[tid] + rr[tid];
    float t1 = xr[tid+256] + rr[tid+256];
    float s = t0 + t1, s2 = t0*t0 + t1*t1;
    __shared__ float red[8];
    s = wred_addf(s); s2 = wred_addf(s2);
    if(lane==0){ red[wave] = s; red[4+wave] = s2; }
    __syncthreads();
    s  = red[0]+red[1]+red[2]+red[3];
    s2 = red[4]+red[5]+red[6]+red[7];
    float mean = s*(1.f/512.f);
    float var = s2*(1.f/512.f) - mean*mean;
    float rs = rsqrtf(var + 1e-5f);
    float o0 = (t0-mean)*rs, o1 = (t1-mean)*rs;
    if(outf){ outf[row*D_+tid] = o0; outf[row*D_+tid+256] = o1; }
    if(outb){ outb[row*D_+tid] = f2bf(o0); outb[row*D_+tid+256] = f2bf(o1); }
}

extern "C" void kernel_launch(void* const* d_in, const int* in_sizes, int n_in,
                              void* d_out, int out_size, void* d_ws, size_t ws_size,
                              hipStream_t stream)
{
    const float* z         = (const float*)d_in[0];
    const float* y         = (const float*)d_in[1];
    const float* graph_dec = (const float*)d_in[2];
    const float* graph_enc = (const float*)d_in[3];
    const float* dec_Wk = (const float*)d_in[4];  const float* dec_bk = (const float*)d_in[5];
    const float* dec_Wv = (const float*)d_in[6];  const float* dec_bv = (const float*)d_in[7];
    const float* dec_Wo = (const float*)d_in[8];  const float* dec_bo = (const float*)d_in[9];
    const float* enc_Wk = (const float*)d_in[10]; const float* enc_bk = (const float*)d_in[11];
    const float* enc_Wq = (const float*)d_in[12]; const float* enc_bq = (const float*)d_in[13];
    const float* enc_Wv = (const float*)d_in[14]; const float* enc_bv = (const float*)d_in[15];
    const float* enc_Wo = (const float*)d_in[16]; const float* enc_bo = (const float*)d_in[17];
    const float* fc_W1  = (const float*)d_in[18]; const float* fc_b1  = (const float*)d_in[19];
    const float* fc_W2  = (const float*)d_in[20]; const float* fc_b2  = (const float*)d_in[21];

    char* ws = (char*)d_ws;
    short* gdec  = (short*)(ws + 0x0000000);
    short* genc  = (short*)(ws + 0x0400000);
    short* y_bf  = (short*)(ws + 0x0800000);
    short* z_bf  = (short*)(ws + 0x0C00000);
    short* Kdec  = (short*)(ws + 0x1000000);
    short* Vtdec = (short*)(ws + 0x1400000);
    short* Kenc  = (short*)(ws + 0x1800000);
    short* Vtenc = (short*)(ws + 0x1C00000);
    short* Qenc  = (short*)(ws + 0x2000000);
    short* ctx   = (short*)(ws + 0x2400000);
    float* tmp   = (float*)(ws + 0x2800000);
    float* hbuf  = (float*)(ws + 0x3000000);
    short* h_bf  = (short*)(ws + 0x3800000);
    float* h2    = (float*)(ws + 0x3C00000);
    short* h2_bf = (short*)(ws + 0x4400000);
    short* fc1   = (short*)(ws + 0x4800000);
    short* wKdt  = (short*)(ws + 0x5800000);
    short* wVdt  = (short*)(ws + 0x5880000);
    short* wOdt  = (short*)(ws + 0x5900000);
    short* wKet  = (short*)(ws + 0x5980000);
    short* wQet  = (short*)(ws + 0x5A00000);
    short* wVet  = (short*)(ws + 0x5A80000);
    short* wOet  = (short*)(ws + 0x5B00000);
    short* wF1t  = (short*)(ws + 0x5B80000);
    short* wF2t  = (short*)(ws + 0x5D80000);
    float* outp  = (float*)d_out;

    dim3 B(256);
    // weight transposes -> bf16 [N][K]
    wtrans_kernel<<<dim3(2,16,8),  B,0,stream>>>(dec_Wk, wKdt, 512,  64, 512*64, 64*512);
    wtrans_kernel<<<dim3(2,16,8),  B,0,stream>>>(dec_Wv, wVdt, 512,  64, 512*64, 64*512);
    wtrans_kernel<<<dim3(16,16,1), B,0,stream>>>(dec_Wo, wOdt, 512, 512, 0, 0);
    wtrans_kernel<<<dim3(2,16,8),  B,0,stream>>>(enc_Wk, wKet, 512,  64, 512*64, 64*512);
    wtrans_kernel<<<dim3(2,16,8),  B,0,stream>>>(enc_Wq, wQet, 512,  64, 512*64, 64*512);
    wtrans_kernel<<<dim3(2,16,8),  B,0,stream>>>(enc_Wv, wVet, 512,  64, 512*64, 64*512);
    wtrans_kernel<<<dim3(16,16,1), B,0,stream>>>(enc_Wo, wOet, 512, 512, 0, 0);
    wtrans_kernel<<<dim3(64,16,1), B,0,stream>>>(fc_W1,  wF1t, 512,2048, 0, 0);
    wtrans_kernel<<<dim3(16,64,1), B,0,stream>>>(fc_W2,  wF2t,2048, 512, 0, 0);
    cvt_bf16_kernel<<<dim3(2048),B,0,stream>>>(y, y_bf, 2097152);
    cvt_bf16_kernel<<<dim3(2048),B,0,stream>>>(z, z_bf, 2097152);
    graph_softmax_kernel<<<dim3(1024,2),B,0,stream>>>(graph_dec, graph_enc, gdec, genc);
    // decoder stage
    gemm_kernel<<<dim3(64,1,8),B,0,stream>>>(y_bf, wKdt, dec_bk, Kdec,  4096,  64,  512, 0, 64*512, 64, 2, 0);
    gemm_kernel<<<dim3(64,1,8),B,0,stream>>>(y_bf, wVdt, dec_bv, Vtdec, 4096,  64,  512, 0, 64*512, 64, 3, 0);
    attn_kernel<<<dim3(128,32),B,0,stream>>>(Kdec, Kdec, Vtdec, gdec, ctx, 1);
    gemm_big_kernel<64,128,0,0><<<dim3(64,4),B,0,stream>>>(ctx, wOdt, dec_bo, tmp, 4096, 512, 512);
    ln_kernel<<<dim3(4096),B,0,stream>>>(tmp, y, hbuf, h_bf);
    // encoder-decoder stage
    gemm_kernel<<<dim3(64,1,8),B,0,stream>>>(z_bf, wKet, enc_bk, Kenc,  4096,  64,  512, 0, 64*512, 64, 2, 0);
    gemm_kernel<<<dim3(64,1,8),B,0,stream>>>(z_bf, wVet, enc_bv, Vtenc, 4096,  64,  512, 0, 64*512, 64, 3, 0);
    gemm_kernel<<<dim3(64,1,8),B,0,stream>>>(h_bf, wQet, enc_bq, Qenc,  4096,  64,  512, 0, 64*512, 64, 2, 0);
    attn_kernel<<<dim3(128,32),B,0,stream>>>(Qenc, Kenc, Vtenc, genc, ctx, 0);
    gemm_big_kernel<64,128,0,0><<<dim3(64,4),B,0,stream>>>(ctx, wOet, enc_bo, tmp, 4096, 512, 512);
    ln_kernel<<<dim3(4096),B,0,stream>>>(tmp, hbuf, h2, h2_bf);
    // MLP
    gemm_big_kernel<128,128,1,1><<<dim3(32,16),B,0,stream>>>(h2_bf, wF1t, fc_b1, fc1, 4096, 2048, 512);
    gemm_big_kernel<64,128,0,0><<<dim3(64,4),B,0,stream>>>(fc1, wF2t, fc_b2, tmp, 4096, 512, 2048);
    ln_kernel<<<dim3(4096),B,0,stream>>>(tmp, h2, outp, (short*)0);
}

// Round 9
// 546.990 us; speedup vs baseline: 1.2322x; 1.0764x over previous
//
#include <hip/hip_runtime.h>
#include <stdint.h>

typedef short short8 __attribute__((ext_vector_type(8)));
typedef short short4v __attribute__((ext_vector_type(4)));
typedef float floatx4 __attribute__((ext_vector_type(4)));

#define H_  8
#define NB_ 4      // batch N
#define S_  1024
#define D_  512
#define KD_ 64

__device__ __forceinline__ short f2bf(float f){
    unsigned u = __builtin_bit_cast(unsigned, f);
    u += 0x7fffu + ((u>>16)&1u);
    return (short)(u>>16);
}
__device__ __forceinline__ float wred_addf(float x){
    #pragma unroll
    for(int o=32;o>0;o>>=1) x += __shfl_xor(x,o,64);
    return x;
}
__device__ __forceinline__ float wred_maxf(float x){
    #pragma unroll
    for(int o=32;o>0;o>>=1) x = fmaxf(x,__shfl_xor(x,o,64));
    return x;
}
// monotone 16-bit key for a bf16 pattern; key 0 only from masked entries
__device__ __forceinline__ unsigned bkey(unsigned u){
    return (u & 0x8000u) ? ((~u) & 0xffffu) : (u | 0x8000u);
}
__device__ __forceinline__ float key2f(unsigned k){
    unsigned u = (k & 0x8000u) ? (k & 0x7fffu) : ((~k) & 0xffffu);
    return __builtin_bit_cast(float, u<<16);
}

// ---------------- fused fp32 -> bf16 for y and z ----------------
__global__ __launch_bounds__(256) void cvt2_kernel(const float* __restrict__ a, const float* __restrict__ b,
                                                   short* __restrict__ oa, short* __restrict__ ob){
    const float* in = blockIdx.y ? b : a;
    short* out = blockIdx.y ? ob : oa;
    int i = (blockIdx.x*256 + threadIdx.x)*4;
    floatx4 v = *(const floatx4*)(in + i);
    short4v r;
    #pragma unroll
    for(int j=0;j<4;j++) r[j] = f2bf(v[j]);
    *(short4v*)(out + i) = r;
}

// ---------------- fused transpose of the 5 per-head [512][64] weights ----------------
// z = 0..39: w = z>>3 in {dec_Wk,dec_Wv,enc_Wk,enc_Wv,enc_Wq}, h = z&7
// dec_Wk/Wv -> wKVd[h][0/64..][512]; enc_Wk/Wv -> wKVe; enc_Wq -> wQet[h][64][512]
__global__ __launch_bounds__(256) void wtrans5_kernel(
    const float* __restrict__ dWk, const float* __restrict__ dWv,
    const float* __restrict__ eWk, const float* __restrict__ eWv, const float* __restrict__ eWq,
    short* __restrict__ wKVd, short* __restrict__ wKVe, short* __restrict__ wQet)
{
    __shared__ float t[32][33];
    int zz = blockIdx.z; int w = zz>>3, h = zz&7;
    const float* src; short* dst;
    if(w==0){ src = dWk + h*32768; dst = wKVd + h*65536; }
    else if(w==1){ src = dWv + h*32768; dst = wKVd + h*65536 + 32768; }
    else if(w==2){ src = eWk + h*32768; dst = wKVe + h*65536; }
    else if(w==3){ src = eWv + h*32768; dst = wKVe + h*65536 + 32768; }
    else { src = eWq + h*32768; dst = wQet + h*32768; }
    const int R = 512, C = 64;
    int c0 = blockIdx.x*32, r0 = blockIdx.y*32;
    int tid = threadIdx.x;
    int r = tid>>3, cq = (tid&7)*4;
    #pragma unroll
    for(int i=0;i<4;i++) t[r][cq+i] = src[(r0+r)*C + c0+cq+i];
    __syncthreads();
    int c = tid>>3, rq = (tid&7)*4;
    #pragma unroll
    for(int i=0;i<4;i++) dst[(c0+c)*R + r0+rq+i] = f2bf(t[rq+i][c]);
}

// ---------------- fused transpose of Wo(dec), Wo(enc), fc_W1, fc_W2 ----------------
// flat grid 2560: [0,256) dec_Wo 512x512; [256,512) enc_Wo; [512,1536) fc1 512x2048; [1536,2560) fc2 2048x512
__global__ __launch_bounds__(256) void wtrans4_kernel(
    const float* __restrict__ dWo, const float* __restrict__ eWo,
    const float* __restrict__ W1, const float* __restrict__ W2,
    short* __restrict__ oWod, short* __restrict__ oWoe,
    short* __restrict__ oW1, short* __restrict__ oW2)
{
    __shared__ float t[32][33];
    int id = blockIdx.x;
    const float* src; short* dst; int R, C, c0, r0;
    if(id < 512){
        src = (id<256)? dWo : eWo; dst = (id<256)? oWod : oWoe;
        int tt = id & 255; R = 512; C = 512;
        c0 = (tt&15)*32; r0 = (tt>>4)*32;
    } else if(id < 1536){
        src = W1; dst = oW1; int tt = id - 512; R = 512; C = 2048;
        c0 = (tt&63)*32; r0 = (tt>>6)*32;
    } else {
        src = W2; dst = oW2; int tt = id - 1536; R = 2048; C = 512;
        c0 = (tt&15)*32; r0 = (tt>>4)*32;
    }
    int tid = threadIdx.x;
    int r = tid>>3, cq = (tid&7)*4;
    #pragma unroll
    for(int i=0;i<4;i++) t[r][cq+i] = src[(long)(r0+r)*C + c0+cq+i];
    __syncthreads();
    int c = tid>>3, rq = (tid&7)*4;
    #pragma unroll
    for(int i=0;i<4;i++) dst[(long)(c0+c)*R + r0+rq+i] = f2bf(t[rq+i][c]);
}

// ---------------- row softmax of the two graphs -> bf16 ----------------
__global__ __launch_bounds__(256) void graph_softmax_kernel(const float* __restrict__ g0,
                                                            const float* __restrict__ g1,
                                                            short* __restrict__ o0,
                                                            short* __restrict__ o1){
    int row = blockIdx.x;
    const float* g = blockIdx.y ? g1 : g0;
    short* o = blockIdx.y ? o1 : o0;
    const float* gr = g + (long)row*S_;
    short* orow = o + (long)row*S_;
    int tid = threadIdx.x, wave = tid>>6, lane = tid&63;
    __shared__ float red[8];
    float v[4]; float mx = -3.0e38f;
    #pragma unroll
    for(int i=0;i<4;i++){ v[i] = gr[tid + 256*i]; mx = fmaxf(mx, v[i]); }
    mx = wred_maxf(mx);
    if(lane==0) red[wave] = mx;
    __syncthreads();
    mx = fmaxf(fmaxf(red[0],red[1]), fmaxf(red[2],red[3]));
    float s = 0.f;
    #pragma unroll
    for(int i=0;i<4;i++){ v[i] = __expf(v[i]-mx); s += v[i]; }
    s = wred_addf(s);
    if(lane==0) red[4+wave] = s;
    __syncthreads();
    s = red[4]+red[5]+red[6]+red[7];
    float inv = 1.f/s;
    #pragma unroll
    for(int i=0;i<4;i++) orow[tid + 256*i] = f2bf(v[i]*inv);
}

// ---------------- fused K+V projection: A[4096][512] x wKV[head][128][512]^T ----------------
// grid (64, 2, 8): half=0 -> K layout, half=1 -> Vt layout
__global__ __launch_bounds__(256) void gemm_kv_kernel(
    const short* __restrict__ A, const short* __restrict__ KVt,
    const float* __restrict__ bk, const float* __restrict__ bv,
    short* __restrict__ outK, short* __restrict__ outV)
{
    int z = blockIdx.z, half = blockIdx.y;
    const short* Bb = KVt + z*65536 + half*32768;
    const float* bb = (half ? bv : bk) + z*64;
    int m0 = blockIdx.x*64;
    int tid = threadIdx.x, wave = tid>>6, lane = tid&63;
    int quad = lane>>4, nl = lane&15;
    int wm = (wave&1)*32, wn = (wave>>1)*32;
    floatx4 acc[2][2];
    #pragma unroll
    for(int i=0;i<2;i++)
        #pragma unroll
        for(int j=0;j<2;j++) acc[i][j] = (floatx4){0.f,0.f,0.f,0.f};
    const short* Aptr0 = A + (long)(m0 + wm + nl)*512 + quad*8;
    const short* Aptr1 = Aptr0 + 16*512;
    const short* Bptr0 = Bb + (long)(wn + nl)*512 + quad*8;
    const short* Bptr1 = Bptr0 + 16*512;
    for(int k0=0;k0<512;k0+=32){
        short8 a0 = *(const short8*)(Aptr0 + k0);
        short8 a1 = *(const short8*)(Aptr1 + k0);
        short8 b0 = *(const short8*)(Bptr0 + k0);
        short8 b1 = *(const short8*)(Bptr1 + k0);
        acc[0][0] = __builtin_amdgcn_mfma_f32_16x16x32_bf16(a0,b0,acc[0][0],0,0,0);
        acc[0][1] = __builtin_amdgcn_mfma_f32_16x16x32_bf16(a0,b1,acc[0][1],0,0,0);
        acc[1][0] = __builtin_amdgcn_mfma_f32_16x16x32_bf16(a1,b0,acc[1][0],0,0,0);
        acc[1][1] = __builtin_amdgcn_mfma_f32_16x16x32_bf16(a1,b1,acc[1][1],0,0,0);
    }
    #pragma unroll
    for(int i=0;i<2;i++){
        #pragma unroll
        for(int j=0;j<2;j++){
            int n = wn + j*16 + nl;
            float bvv = bb[n];
            #pragma unroll
            for(int r=0;r<4;r++){
                int m = m0 + wm + i*16 + quad*4 + r;
                float v = acc[i][j][r] + bvv;
                if(!half) outK[ ((long)(z*NB_ + (m>>10))*S_ + (m&1023))*KD_ + n ] = f2bf(v);
                else      outV[ ((long)(z*NB_ + (m>>10))*KD_ + n)*S_ + (m&1023) ] = f2bf(v);
            }
        }
    }
}

// ---------------- small bf16 MFMA GEMM (direct-global): Q projection (mode2) ----------------
__global__ __launch_bounds__(256) void gemm_kernel(
    const short* __restrict__ A, const short* __restrict__ Bt, const float* __restrict__ bias,
    short* __restrict__ out, int K, long batchB, long batchBias)
{
    int z = blockIdx.z;
    const short* Bb = Bt + (long)z*batchB;
    const float* bb = bias + (long)z*batchBias;
    int m0 = blockIdx.x*64;
    int tid = threadIdx.x, wave = tid>>6, lane = tid&63;
    int quad = lane>>4, nl = lane&15;
    int wm = (wave&1)*32, wn = (wave>>1)*32;
    floatx4 acc[2][2];
    #pragma unroll
    for(int i=0;i<2;i++)
        #pragma unroll
        for(int j=0;j<2;j++) acc[i][j] = (floatx4){0.f,0.f,0.f,0.f};
    const short* Aptr0 = A + (long)(m0 + wm + nl)*K + quad*8;
    const short* Aptr1 = Aptr0 + 16*(long)K;
    const short* Bptr0 = Bb + (long)(wn + nl)*K + quad*8;
    const short* Bptr1 = Bptr0 + 16*(long)K;
    for(int k0=0;k0<K;k0+=32){
        short8 a0 = *(const short8*)(Aptr0 + k0);
        short8 a1 = *(const short8*)(Aptr1 + k0);
        short8 b0 = *(const short8*)(Bptr0 + k0);
        short8 b1 = *(const short8*)(Bptr1 + k0);
        acc[0][0] = __builtin_amdgcn_mfma_f32_16x16x32_bf16(a0,b0,acc[0][0],0,0,0);
        acc[0][1] = __builtin_amdgcn_mfma_f32_16x16x32_bf16(a0,b1,acc[0][1],0,0,0);
        acc[1][0] = __builtin_amdgcn_mfma_f32_16x16x32_bf16(a1,b0,acc[1][0],0,0,0);
        acc[1][1] = __builtin_amdgcn_mfma_f32_16x16x32_bf16(a1,b1,acc[1][1],0,0,0);
    }
    #pragma unroll
    for(int i=0;i<2;i++){
        #pragma unroll
        for(int j=0;j<2;j++){
            int n = wn + j*16 + nl;
            float bv = bb[n];
            #pragma unroll
            for(int r=0;r<4;r++){
                int m = m0 + wm + i*16 + quad*4 + r;
                float v = acc[i][j][r] + bv;
                out[ ((long)(z*NB_ + (m>>10))*S_ + (m&1023))*KD_ + n ] = f2bf(v);
            }
        }
    }
}

// ---------------- big MFMA GEMM, m97 pattern ----------------
template<int TM, int TN, int OUTBF, int RELU>
__global__ __launch_bounds__(256) void gemm_big_kernel(
    const short* __restrict__ A, const short* __restrict__ Bt, const float* __restrict__ bias,
    void* __restrict__ out, int M, int N, int K)
{
    __shared__ short As[TM*32];
    __shared__ short Bs[TN*32];
    int m0 = blockIdx.x*TM, n0 = blockIdx.y*TN;
    int tid = threadIdx.x, wave = tid>>6, lane = tid&63, quad = lane>>4, nl = lane&15;
    constexpr int MI = TM/32, NI = TN/32;
    int wm = (wave&1)*(TM/2), wn = (wave>>1)*(TN/2);
    floatx4 acc[MI][NI];
    #pragma unroll
    for(int i=0;i<MI;i++)
        #pragma unroll
        for(int j=0;j<NI;j++) acc[i][j] = (floatx4){0.f,0.f,0.f,0.f};

    int r = tid>>2, c = (tid&3)*8;
    for(int k0=0;k0<K;k0+=32){
        __syncthreads();
        #pragma unroll
        for(int i=0;i<TM/64;i++)
            __builtin_amdgcn_global_load_lds(
                (const __attribute__((address_space(1))) unsigned*)(A + (long)(m0 + r + i*64)*K + k0 + c),
                (__attribute__((address_space(3))) unsigned*)((char*)As + i*4096 + wave*1024),
                16, 0, 0);
        #pragma unroll
        for(int i=0;i<TN/64;i++)
            __builtin_amdgcn_global_load_lds(
                (const __attribute__((address_space(1))) unsigned*)(Bt + (long)(n0 + r + i*64)*K + k0 + c),
                (__attribute__((address_space(3))) unsigned*)((char*)Bs + i*4096 + wave*1024),
                16, 0, 0);
        __syncthreads();
        short8 af[MI], bfr[NI];
        #pragma unroll
        for(int i=0;i<MI;i++) af[i] = *(const short8*)(As + (wm + i*16 + nl)*32 + quad*8);
        #pragma unroll
        for(int j=0;j<NI;j++) bfr[j] = *(const short8*)(Bs + (wn + j*16 + nl)*32 + quad*8);
        #pragma unroll
        for(int i=0;i<MI;i++)
            #pragma unroll
            for(int j=0;j<NI;j++)
                acc[i][j] = __builtin_amdgcn_mfma_f32_16x16x32_bf16(af[i],bfr[j],acc[i][j],0,0,0);
    }
    #pragma unroll
    for(int j=0;j<NI;j++){
        int n = n0 + wn + j*16 + nl;
        float bv = bias[n];
        #pragma unroll
        for(int i=0;i<MI;i++){
            #pragma unroll
            for(int rr=0;rr<4;rr++){
                int m = m0 + wm + i*16 + quad*4 + rr;
                float v = acc[i][j][rr] + bv;
                if(RELU) v = fmaxf(v, 0.f);
                if(OUTBF) ((short*)out)[(long)m*N + n] = f2bf(v);
                else      ((float*)out)[(long)m*N + n] = v;
            }
        }
    }
}

// ---------------- fused attention v5: XCD-swizzled grid (hn fastest) ----------------
// grid (32, 128): blockIdx.x = hn (id%8 = hn%8 -> all qt of a head on one XCD, K+V L2-resident),
// blockIdx.y = qt. 8 q-rows/block, 16 KiB LDS.
__global__ __launch_bounds__(256,4) void attn_kernel(
    const short* __restrict__ Qb, const short* __restrict__ Kb, const short* __restrict__ Vt,
    const short* __restrict__ graph, short* __restrict__ ctx, int causal)
{
    __shared__ short attb[8*1024];   // 16 KiB
    int hn = blockIdx.x, qt = blockIdx.y;
    int h = hn>>2, n = hn&3;
    int q0 = qt*8;
    int tid=threadIdx.x, wave=tid>>6, lane=tid&63, quad=lane>>4, nl=lane&15;

    // ---- phase 1: scores -> bf16 LDS (rot 8q) ----
    const short* Qp = Qb + ((long)hn*S_ + q0 + (nl&7))*KD_ + quad*8;
    short8 aq0 = *(const short8*)(Qp);
    short8 aq1 = *(const short8*)(Qp + 32);
    const short* Kp = Kb + (long)hn*S_*KD_;
    int stmax = causal ? ((q0+7)>>4) : 63;
    for(int st=wave; st<=stmax; st+=4){
        const short* kp = Kp + (st*16 + nl)*KD_ + quad*8;
        short8 b0 = *(const short8*)(kp);
        short8 b1 = *(const short8*)(kp + 32);
        floatx4 cc = (floatx4){0.f,0.f,0.f,0.f};
        cc = __builtin_amdgcn_mfma_f32_16x16x32_bf16(aq0,b0,cc,0,0,0);
        cc = __builtin_amdgcn_mfma_f32_16x16x32_bf16(aq1,b1,cc,0,0,0);
        #pragma unroll
        for(int rr=0;rr<4;rr++){
            int q = quad*4 + rr, s = st*16 + nl;
            if(q < 8) attb[q*1024 + ((s + 8*q)&1023)] = f2bf(cc[rr]*0.125f);
        }
    }
    __syncthreads();

    // ---- phase 2: selection + softmax + blend (2 rows/wave via 32-lane groups) ----
    {
        int g = lane>>5, li = lane&31;
        int q = wave*2 + g;
        int qg = q0 + q;
        int slimit = causal ? qg : 1023;
        short* rowp = attb + q*1024;
        unsigned mv[32];
        unsigned mk = 0u;
        #pragma unroll
        for(int t=0;t<2;t++){
            int sb = li*16 + t*512;
            int p0 = (sb + 8*q) & 1023;
            short8 c0 = *(const short8*)(rowp + p0);
            short8 c1 = *(const short8*)(rowp + ((p0+8)&1023));
            #pragma unroll
            for(int j=0;j<8;j++){
                unsigned k0 = (sb+j   <= slimit) ? bkey((unsigned)(unsigned short)c0[j]) : 0u;
                unsigned k1 = (sb+8+j <= slimit) ? bkey((unsigned)(unsigned short)c1[j]) : 0u;
                mv[t*16+j]   = k0; mk = k0>mk?k0:mk;
                mv[t*16+8+j] = k1; mk = k1>mk?k1:mk;
            }
        }
        #pragma unroll
        for(int j=0;j<32;j++) asm volatile("" : "+v"(mv[j]));
        // group max (5-deep, stays within 32-lane group)
        #pragma unroll
        for(int o=1;o<=16;o<<=1){ unsigned tt=__shfl_xor(mk,o,64); mk = tt>mk?tt:mk; }
        unsigned lo=0u, hi=mk+1u;
        for(int it=0; it<16; ++it){
            unsigned mid = lo + ((hi-lo)>>1);
            unsigned cnt = 0u;
            #pragma unroll
            for(int j=0;j<32;j++) cnt += (mv[j] >= mid) ? 1u : 0u;
            #pragma unroll
            for(int o=1;o<=16;o<<=1) cnt += __shfl_xor(cnt,o,64);
            bool ge = (cnt >= 128u);
            bool eq = (cnt == 128u);
            lo = ge ? mid : lo;
            hi = ge ? (eq ? mid+1u : hi) : mid;
        }
        // exp + sum (stash exp back into mv)
        float mxf = key2f(mk);
        float sm = 0.f;
        #pragma unroll
        for(int j=0;j<32;j++){
            unsigned k = mv[j];
            float e = (k >= lo && k != 0u) ? __expf(key2f(k)-mxf) : 0.f;
            mv[j] = __builtin_bit_cast(unsigned, e);
            sm += e;
        }
        #pragma unroll
        for(int o=1;o<=16;o<<=1) sm += __shfl_xor(sm,o,64);
        float inv = 0.5f/sm;   // (1-gw)=0.5
        const short* grow = graph + (long)qg*1024;
        #pragma unroll
        for(int t=0;t<2;t++){
            int sb = li*16 + t*512;
            short8 g0 = *(const short8*)(grow + sb);
            short8 g1 = *(const short8*)(grow + sb + 8);
            short8 o0, o1;
            #pragma unroll
            for(int j=0;j<8;j++){
                float gv0 = __builtin_bit_cast(float, ((unsigned)(unsigned short)g0[j])<<16);
                float gv1 = __builtin_bit_cast(float, ((unsigned)(unsigned short)g1[j])<<16);
                float e0 = __builtin_bit_cast(float, mv[t*16+j]);
                float e1 = __builtin_bit_cast(float, mv[t*16+8+j]);
                o0[j] = f2bf(0.5f*gv0 + e0*inv);
                o1[j] = f2bf(0.5f*gv1 + e1*inv);
            }
            int p0 = (sb + 8*q) & 1023;
            *(short8*)(rowp + p0) = o0;
            *(short8*)(rowp + ((p0+8)&1023)) = o1;
        }
    }
    __syncthreads();

    // ---- phase 3: ctx = att @ V (rows duplicated nl&7, writes guarded) ----
    int v0 = wave*16;
    const short* Vp = Vt + ((long)hn*KD_ + v0 + nl)*S_;
    floatx4 o4 = (floatx4){0.f,0.f,0.f,0.f};
    int arow = nl & 7;
    for(int s0=0; s0<1024; s0+=32){
        int cs = (s0 + quad*8 + 8*arow) & 1023;
        short8 ap = *(const short8*)(attb + arow*1024 + cs);
        short8 bv = *(const short8*)(Vp + s0 + quad*8);
        o4 = __builtin_amdgcn_mfma_f32_16x16x32_bf16(ap,bv,o4,0,0,0);
    }
    #pragma unroll
    for(int rr=0;rr<4;rr++){
        int q = quad*4 + rr;
        if(q < 8)
            ctx[ ((long)(n*S_ + q0 + q))*512 + h*KD_ + v0 + nl ] = f2bf(o4[rr]);
    }
}

// ---------------- LayerNorm(x + res) ----------------
__global__ __launch_bounds__(256) void ln_kernel(const float* __restrict__ x, const float* __restrict__ res,
                                                 float* __restrict__ outf, short* __restrict__ outb){
    long row = blockIdx.x;
    const float* xr = x + row*D_;
    const float* rr = res + row*D_;
    int tid = threadIdx.x, wave = tid>>6, lane = tid&63;
    float t0 = xr[tid] + rr[tid];
    float t1 = xr[tid+256] + rr[tid+256];
    float s = t0 + t1, s2 = t0*t0 + t1*t1;
    __shared__ float red[8];
    s = wred_addf(s); s2 = wred_addf(s2);
    if(lane==0){ red[wave] = s; red[4+wave] = s2; }
    __syncthreads();
    s  = red[0]+red[1]+red[2]+red[3];
    s2 = red[4]+red[5]+red[6]+red[7];
    float mean = s*(1.f/512.f);
    float var = s2*(1.f/512.f) - mean*mean;
    float rs = rsqrtf(var + 1e-5f);
    float o0 = (t0-mean)*rs, o1 = (t1-mean)*rs;
    if(outf){ outf[row*D_+tid] = o0; outf[row*D_+tid+256] = o1; }
    if(outb){ outb[row*D_+tid] = f2bf(o0); outb[row*D_+tid+256] = f2bf(o1); }
}

extern "C" void kernel_launch(void* const* d_in, const int* in_sizes, int n_in,
                              void* d_out, int out_size, void* d_ws, size_t ws_size,
                              hipStream_t stream)
{
    const float* z         = (const float*)d_in[0];
    const float* y         = (const float*)d_in[1];
    const float* graph_dec = (const float*)d_in[2];
    const float* graph_enc = (const float*)d_in[3];
    const float* dec_Wk = (const float*)d_in[4];  const float* dec_bk = (const float*)d_in[5];
    const float* dec_Wv = (const float*)d_in[6];  const float* dec_bv = (const float*)d_in[7];
    const float* dec_Wo = (const float*)d_in[8];  const float* dec_bo = (const float*)d_in[9];
    const float* enc_Wk = (const float*)d_in[10]; const float* enc_bk = (const float*)d_in[11];
    const float* enc_Wq = (const float*)d_in[12]; const float* enc_bq = (const float*)d_in[13];
    const float* enc_Wv = (const float*)d_in[14]; const float* enc_bv = (const float*)d_in[15];
    const float* enc_Wo = (const float*)d_in[16]; const float* enc_bo = (const float*)d_in[17];
    const float* fc_W1  = (const float*)d_in[18]; const float* fc_b1  = (const float*)d_in[19];
    const float* fc_W2  = (const float*)d_in[20]; const float* fc_b2  = (const float*)d_in[21];

    char* ws = (char*)d_ws;
    short* gdec  = (short*)(ws + 0x0000000);
    short* genc  = (short*)(ws + 0x0400000);
    short* y_bf  = (short*)(ws + 0x0800000);
    short* z_bf  = (short*)(ws + 0x0C00000);
    short* Kdec  = (short*)(ws + 0x1000000);
    short* Vtdec = (short*)(ws + 0x1400000);
    short* Kenc  = (short*)(ws + 0x1800000);
    short* Vtenc = (short*)(ws + 0x1C00000);
    short* Qenc  = (short*)(ws + 0x2000000);
    short* ctx   = (short*)(ws + 0x2400000);
    float* tmp   = (float*)(ws + 0x2800000);
    float* hbuf  = (float*)(ws + 0x3000000);
    short* h_bf  = (short*)(ws + 0x3800000);
    float* h2    = (float*)(ws + 0x3C00000);
    short* h2_bf = (short*)(ws + 0x4400000);
    short* fc1   = (short*)(ws + 0x4800000);
    short* wKVd  = (short*)(ws + 0x5800000);
    short* wKVe  = (short*)(ws + 0x5900000);
    short* wQet  = (short*)(ws + 0x5A00000);
    short* wOdt  = (short*)(ws + 0x5A80000);
    short* wOet  = (short*)(ws + 0x5B00000);
    short* wF1t  = (short*)(ws + 0x5B80000);
    short* wF2t  = (short*)(ws + 0x5D80000);
    float* outp  = (float*)d_out;

    dim3 B(256);
    wtrans5_kernel<<<dim3(2,16,40),B,0,stream>>>(dec_Wk, dec_Wv, enc_Wk, enc_Wv, enc_Wq, wKVd, wKVe, wQet);
    wtrans4_kernel<<<dim3(2560),B,0,stream>>>(dec_Wo, enc_Wo, fc_W1, fc_W2, wOdt, wOet, wF1t, wF2t);
    cvt2_kernel<<<dim3(2048,2),B,0,stream>>>(y, z, y_bf, z_bf);
    graph_softmax_kernel<<<dim3(1024,2),B,0,stream>>>(graph_dec, graph_enc, gdec, genc);
    // decoder stage
    gemm_kv_kernel<<<dim3(64,2,8),B,0,stream>>>(y_bf, wKVd, dec_bk, dec_bv, Kdec, Vtdec);
    attn_kernel<<<dim3(32,128),B,0,stream>>>(Kdec, Kdec, Vtdec, gdec, ctx, 1);
    gemm_big_kernel<64,128,0,0><<<dim3(64,4),B,0,stream>>>(ctx, wOdt, dec_bo, tmp, 4096, 512, 512);
    ln_kernel<<<dim3(4096),B,0,stream>>>(tmp, y, hbuf, h_bf);
    // encoder-decoder stage
    gemm_kv_kernel<<<dim3(64,2,8),B,0,stream>>>(z_bf, wKVe, enc_bk, enc_bv, Kenc, Vtenc);
    gemm_kernel<<<dim3(64,1,8),B,0,stream>>>(h_bf, wQet, enc_bq, Qenc, 512, 64*512, 64);
    attn_kernel<<<dim3(32,128),B,0,stream>>>(Qenc, Kenc, Vtenc, genc, ctx, 0);
    gemm_big_kernel<64,128,0,0><<<dim3(64,4),B,0,stream>>>(ctx, wOet, enc_bo, tmp, 4096, 512, 512);
    ln_kernel<<<dim3(4096),B,0,stream>>>(tmp, hbuf, h2, h2_bf);
    // MLP
    gemm_big_kernel<128,128,1,1><<<dim3(32,16),B,0,stream>>>(h2_bf, wF1t, fc_b1, fc1, 4096, 2048, 512);
    gemm_big_kernel<64,128,0,0><<<dim3(64,4),B,0,stream>>>(fc1, wF2t, fc_b2, tmp, 4096, 512, 2048);
    ln_kernel<<<dim3(4096),B,0,stream>>>(tmp, h2, outp, (short*)0);
}

// Round 10
// 466.884 us; speedup vs baseline: 1.4436x; 1.1716x over previous
//
#include <hip/hip_runtime.h>
#include <stdint.h>

typedef short short8 __attribute__((ext_vector_type(8)));
typedef short short4v __attribute__((ext_vector_type(4)));
typedef float floatx4 __attribute__((ext_vector_type(4)));

#define H_  8
#define NB_ 4      // batch N
#define S_  1024
#define D_  512
#define KD_ 64

__device__ __forceinline__ short f2bf(float f){
    unsigned u = __builtin_bit_cast(unsigned, f);
    u += 0x7fffu + ((u>>16)&1u);
    return (short)(u>>16);
}
__device__ __forceinline__ float wred_addf(float x){
    #pragma unroll
    for(int o=32;o>0;o>>=1) x += __shfl_xor(x,o,64);
    return x;
}
__device__ __forceinline__ float wred_maxf(float x){
    #pragma unroll
    for(int o=32;o>0;o>>=1) x = fmaxf(x,__shfl_xor(x,o,64));
    return x;
}
// monotone 16-bit key for a bf16 pattern; key 0 only from masked entries
__device__ __forceinline__ unsigned bkey(unsigned u){
    return (u & 0x8000u) ? ((~u) & 0xffffu) : (u | 0x8000u);
}
__device__ __forceinline__ float key2f(unsigned k){
    unsigned u = (k & 0x8000u) ? (k & 0x7fffu) : ((~k) & 0xffffu);
    return __builtin_bit_cast(float, u<<16);
}

// ---------------- fused fp32 -> bf16 for y and z ----------------
__global__ __launch_bounds__(256) void cvt2_kernel(const float* __restrict__ a, const float* __restrict__ b,
                                                   short* __restrict__ oa, short* __restrict__ ob){
    const float* in = blockIdx.y ? b : a;
    short* out = blockIdx.y ? ob : oa;
    int i = (blockIdx.x*256 + threadIdx.x)*4;
    floatx4 v = *(const floatx4*)(in + i);
    short4v r;
    #pragma unroll
    for(int j=0;j<4;j++) r[j] = f2bf(v[j]);
    *(short4v*)(out + i) = r;
}

// ---------------- fused transpose of the 5 per-head [512][64] weights ----------------
__global__ __launch_bounds__(256) void wtrans5_kernel(
    const float* __restrict__ dWk, const float* __restrict__ dWv,
    const float* __restrict__ eWk, const float* __restrict__ eWv, const float* __restrict__ eWq,
    short* __restrict__ wKVd, short* __restrict__ wKVe, short* __restrict__ wQet)
{
    __shared__ float t[32][33];
    int zz = blockIdx.z; int w = zz>>3, h = zz&7;
    const float* src; short* dst;
    if(w==0){ src = dWk + h*32768; dst = wKVd + h*65536; }
    else if(w==1){ src = dWv + h*32768; dst = wKVd + h*65536 + 32768; }
    else if(w==2){ src = eWk + h*32768; dst = wKVe + h*65536; }
    else if(w==3){ src = eWv + h*32768; dst = wKVe + h*65536 + 32768; }
    else { src = eWq + h*32768; dst = wQet + h*32768; }
    const int R = 512, C = 64;
    int c0 = blockIdx.x*32, r0 = blockIdx.y*32;
    int tid = threadIdx.x;
    int r = tid>>3, cq = (tid&7)*4;
    #pragma unroll
    for(int i=0;i<4;i++) t[r][cq+i] = src[(r0+r)*C + c0+cq+i];
    __syncthreads();
    int c = tid>>3, rq = (tid&7)*4;
    #pragma unroll
    for(int i=0;i<4;i++) dst[(c0+c)*R + r0+rq+i] = f2bf(t[rq+i][c]);
}

// ---------------- fused transpose of Wo(dec), Wo(enc), fc_W1, fc_W2 ----------------
__global__ __launch_bounds__(256) void wtrans4_kernel(
    const float* __restrict__ dWo, const float* __restrict__ eWo,
    const float* __restrict__ W1, const float* __restrict__ W2,
    short* __restrict__ oWod, short* __restrict__ oWoe,
    short* __restrict__ oW1, short* __restrict__ oW2)
{
    __shared__ float t[32][33];
    int id = blockIdx.x;
    const float* src; short* dst; int R, C, c0, r0;
    if(id < 512){
        src = (id<256)? dWo : eWo; dst = (id<256)? oWod : oWoe;
        int tt = id & 255; R = 512; C = 512;
        c0 = (tt&15)*32; r0 = (tt>>4)*32;
    } else if(id < 1536){
        src = W1; dst = oW1; int tt = id - 512; R = 512; C = 2048;
        c0 = (tt&63)*32; r0 = (tt>>6)*32;
    } else {
        src = W2; dst = oW2; int tt = id - 1536; R = 2048; C = 512;
        c0 = (tt&15)*32; r0 = (tt>>4)*32;
    }
    int tid = threadIdx.x;
    int r = tid>>3, cq = (tid&7)*4;
    #pragma unroll
    for(int i=0;i<4;i++) t[r][cq+i] = src[(long)(r0+r)*C + c0+cq+i];
    __syncthreads();
    int c = tid>>3, rq = (tid&7)*4;
    #pragma unroll
    for(int i=0;i<4;i++) dst[(long)(c0+c)*R + r0+rq+i] = f2bf(t[rq+i][c]);
}

// ---------------- row softmax of the two graphs -> bf16 ----------------
__global__ __launch_bounds__(256) void graph_softmax_kernel(const float* __restrict__ g0,
                                                            const float* __restrict__ g1,
                                                            short* __restrict__ o0,
                                                            short* __restrict__ o1){
    int row = blockIdx.x;
    const float* g = blockIdx.y ? g1 : g0;
    short* o = blockIdx.y ? o1 : o0;
    const float* gr = g + (long)row*S_;
    short* orow = o + (long)row*S_;
    int tid = threadIdx.x, wave = tid>>6, lane = tid&63;
    __shared__ float red[8];
    float v[4]; float mx = -3.0e38f;
    #pragma unroll
    for(int i=0;i<4;i++){ v[i] = gr[tid + 256*i]; mx = fmaxf(mx, v[i]); }
    mx = wred_maxf(mx);
    if(lane==0) red[wave] = mx;
    __syncthreads();
    mx = fmaxf(fmaxf(red[0],red[1]), fmaxf(red[2],red[3]));
    float s = 0.f;
    #pragma unroll
    for(int i=0;i<4;i++){ v[i] = __expf(v[i]-mx); s += v[i]; }
    s = wred_addf(s);
    if(lane==0) red[4+wave] = s;
    __syncthreads();
    s = red[4]+red[5]+red[6]+red[7];
    float inv = 1.f/s;
    #pragma unroll
    for(int i=0;i<4;i++) orow[tid + 256*i] = f2bf(v[i]*inv);
}

// ---------------- fused K+V projection ----------------
__global__ __launch_bounds__(256) void gemm_kv_kernel(
    const short* __restrict__ A, const short* __restrict__ KVt,
    const float* __restrict__ bk, const float* __restrict__ bv,
    short* __restrict__ outK, short* __restrict__ outV)
{
    int z = blockIdx.z, half = blockIdx.y;
    const short* Bb = KVt + z*65536 + half*32768;
    const float* bb = (half ? bv : bk) + z*64;
    int m0 = blockIdx.x*64;
    int tid = threadIdx.x, wave = tid>>6, lane = tid&63;
    int quad = lane>>4, nl = lane&15;
    int wm = (wave&1)*32, wn = (wave>>1)*32;
    floatx4 acc[2][2];
    #pragma unroll
    for(int i=0;i<2;i++)
        #pragma unroll
        for(int j=0;j<2;j++) acc[i][j] = (floatx4){0.f,0.f,0.f,0.f};
    const short* Aptr0 = A + (long)(m0 + wm + nl)*512 + quad*8;
    const short* Aptr1 = Aptr0 + 16*512;
    const short* Bptr0 = Bb + (long)(wn + nl)*512 + quad*8;
    const short* Bptr1 = Bptr0 + 16*512;
    for(int k0=0;k0<512;k0+=32){
        short8 a0 = *(const short8*)(Aptr0 + k0);
        short8 a1 = *(const short8*)(Aptr1 + k0);
        short8 b0 = *(const short8*)(Bptr0 + k0);
        short8 b1 = *(const short8*)(Bptr1 + k0);
        acc[0][0] = __builtin_amdgcn_mfma_f32_16x16x32_bf16(a0,b0,acc[0][0],0,0,0);
        acc[0][1] = __builtin_amdgcn_mfma_f32_16x16x32_bf16(a0,b1,acc[0][1],0,0,0);
        acc[1][0] = __builtin_amdgcn_mfma_f32_16x16x32_bf16(a1,b0,acc[1][0],0,0,0);
        acc[1][1] = __builtin_amdgcn_mfma_f32_16x16x32_bf16(a1,b1,acc[1][1],0,0,0);
    }
    #pragma unroll
    for(int i=0;i<2;i++){
        #pragma unroll
        for(int j=0;j<2;j++){
            int n = wn + j*16 + nl;
            float bvv = bb[n];
            #pragma unroll
            for(int r=0;r<4;r++){
                int m = m0 + wm + i*16 + quad*4 + r;
                float v = acc[i][j][r] + bvv;
                if(!half) outK[ ((long)(z*NB_ + (m>>10))*S_ + (m&1023))*KD_ + n ] = f2bf(v);
                else      outV[ ((long)(z*NB_ + (m>>10))*KD_ + n)*S_ + (m&1023) ] = f2bf(v);
            }
        }
    }
}

// ---------------- small bf16 MFMA GEMM: Q projection ----------------
__global__ __launch_bounds__(256) void gemm_kernel(
    const short* __restrict__ A, const short* __restrict__ Bt, const float* __restrict__ bias,
    short* __restrict__ out, int K, long batchB, long batchBias)
{
    int z = blockIdx.z;
    const short* Bb = Bt + (long)z*batchB;
    const float* bb = bias + (long)z*batchBias;
    int m0 = blockIdx.x*64;
    int tid = threadIdx.x, wave = tid>>6, lane = tid&63;
    int quad = lane>>4, nl = lane&15;
    int wm = (wave&1)*32, wn = (wave>>1)*32;
    floatx4 acc[2][2];
    #pragma unroll
    for(int i=0;i<2;i++)
        #pragma unroll
        for(int j=0;j<2;j++) acc[i][j] = (floatx4){0.f,0.f,0.f,0.f};
    const short* Aptr0 = A + (long)(m0 + wm + nl)*K + quad*8;
    const short* Aptr1 = Aptr0 + 16*(long)K;
    const short* Bptr0 = Bb + (long)(wn + nl)*K + quad*8;
    const short* Bptr1 = Bptr0 + 16*(long)K;
    for(int k0=0;k0<K;k0+=32){
        short8 a0 = *(const short8*)(Aptr0 + k0);
        short8 a1 = *(const short8*)(Aptr1 + k0);
        short8 b0 = *(const short8*)(Bptr0 + k0);
        short8 b1 = *(const short8*)(Bptr1 + k0);
        acc[0][0] = __builtin_amdgcn_mfma_f32_16x16x32_bf16(a0,b0,acc[0][0],0,0,0);
        acc[0][1] = __builtin_amdgcn_mfma_f32_16x16x32_bf16(a0,b1,acc[0][1],0,0,0);
        acc[1][0] = __builtin_amdgcn_mfma_f32_16x16x32_bf16(a1,b0,acc[1][0],0,0,0);
        acc[1][1] = __builtin_amdgcn_mfma_f32_16x16x32_bf16(a1,b1,acc[1][1],0,0,0);
    }
    #pragma unroll
    for(int i=0;i<2;i++){
        #pragma unroll
        for(int j=0;j<2;j++){
            int n = wn + j*16 + nl;
            float bv = bb[n];
            #pragma unroll
            for(int r=0;r<4;r++){
                int m = m0 + wm + i*16 + quad*4 + r;
                float v = acc[i][j][r] + bv;
                out[ ((long)(z*NB_ + (m>>10))*S_ + (m&1023))*KD_ + n ] = f2bf(v);
            }
        }
    }
}

// ---------------- big MFMA GEMM, m97 pattern ----------------
template<int TM, int TN, int OUTBF, int RELU>
__global__ __launch_bounds__(256) void gemm_big_kernel(
    const short* __restrict__ A, const short* __restrict__ Bt, const float* __restrict__ bias,
    void* __restrict__ out, int M, int N, int K)
{
    __shared__ short As[TM*32];
    __shared__ short Bs[TN*32];
    int m0 = blockIdx.x*TM, n0 = blockIdx.y*TN;
    int tid = threadIdx.x, wave = tid>>6, lane = tid&63, quad = lane>>4, nl = lane&15;
    constexpr int MI = TM/32, NI = TN/32;
    int wm = (wave&1)*(TM/2), wn = (wave>>1)*(TN/2);
    floatx4 acc[MI][NI];
    #pragma unroll
    for(int i=0;i<MI;i++)
        #pragma unroll
        for(int j=0;j<NI;j++) acc[i][j] = (floatx4){0.f,0.f,0.f,0.f};

    int r = tid>>2, c = (tid&3)*8;
    for(int k0=0;k0<K;k0+=32){
        __syncthreads();
        #pragma unroll
        for(int i=0;i<TM/64;i++)
            __builtin_amdgcn_global_load_lds(
                (const __attribute__((address_space(1))) unsigned*)(A + (long)(m0 + r + i*64)*K + k0 + c),
                (__attribute__((address_space(3))) unsigned*)((char*)As + i*4096 + wave*1024),
                16, 0, 0);
        #pragma unroll
        for(int i=0;i<TN/64;i++)
            __builtin_amdgcn_global_load_lds(
                (const __attribute__((address_space(1))) unsigned*)(Bt + (long)(n0 + r + i*64)*K + k0 + c),
                (__attribute__((address_space(3))) unsigned*)((char*)Bs + i*4096 + wave*1024),
                16, 0, 0);
        __syncthreads();
        short8 af[MI], bfr[NI];
        #pragma unroll
        for(int i=0;i<MI;i++) af[i] = *(const short8*)(As + (wm + i*16 + nl)*32 + quad*8);
        #pragma unroll
        for(int j=0;j<NI;j++) bfr[j] = *(const short8*)(Bs + (wn + j*16 + nl)*32 + quad*8);
        #pragma unroll
        for(int i=0;i<MI;i++)
            #pragma unroll
            for(int j=0;j<NI;j++)
                acc[i][j] = __builtin_amdgcn_mfma_f32_16x16x32_bf16(af[i],bfr[j],acc[i][j],0,0,0);
    }
    #pragma unroll
    for(int j=0;j<NI;j++){
        int n = n0 + wn + j*16 + nl;
        float bv = bias[n];
        #pragma unroll
        for(int i=0;i<MI;i++){
            #pragma unroll
            for(int rr=0;rr<4;rr++){
                int m = m0 + wm + i*16 + quad*4 + rr;
                float v = acc[i][j][rr] + bv;
                if(RELU) v = fmaxf(v, 0.f);
                if(OUTBF) ((short*)out)[(long)m*N + n] = f2bf(v);
                else      ((float*)out)[(long)m*N + n] = v;
            }
        }
    }
}

// ---------------- fused attention v6: 16 q-rows/block, 512 threads, 36 KiB LDS ----------------
// grid (32, 64): blockIdx.x = hn (XCD swizzle), blockIdx.y = qt. 8 waves.
// Phase 1: QK^T/8 -> bf16 LDS, all 16 A-rows real. Phase 2: 2 rows/wave via 32-lane
// groups (8 waves x 2 = 16). Phase 3: split s-halves across wave pairs, partial
// accumulation through padded LDS buffer.
__global__ __launch_bounds__(512) void attn_kernel(
    const short* __restrict__ Qb, const short* __restrict__ Kb, const short* __restrict__ Vt,
    const short* __restrict__ graph, short* __restrict__ ctx, int causal)
{
    __shared__ short attb[16*1024];   // 32 KiB
    __shared__ float pbuf[16*68];     // 4.25 KiB, padded rows (68) -> 2-way max on partial store
    int hn = blockIdx.x, qt = blockIdx.y;
    int h = hn>>2, n = hn&3;
    int q0 = qt*16;
    int tid=threadIdx.x, wave=tid>>6, lane=tid&63, quad=lane>>4, nl=lane&15;

    // ---- phase 1: scores -> bf16 LDS (rot 8q), 16 real rows ----
    const short* Qp = Qb + ((long)hn*S_ + q0 + nl)*KD_ + quad*8;
    short8 aq0 = *(const short8*)(Qp);
    short8 aq1 = *(const short8*)(Qp + 32);
    const short* Kp = Kb + (long)hn*S_*KD_;
    int stmax = causal ? qt : 63;
    for(int st=wave; st<=stmax; st+=8){
        const short* kp = Kp + (st*16 + nl)*KD_ + quad*8;
        short8 b0 = *(const short8*)(kp);
        short8 b1 = *(const short8*)(kp + 32);
        floatx4 cc = (floatx4){0.f,0.f,0.f,0.f};
        cc = __builtin_amdgcn_mfma_f32_16x16x32_bf16(aq0,b0,cc,0,0,0);
        cc = __builtin_amdgcn_mfma_f32_16x16x32_bf16(aq1,b1,cc,0,0,0);
        #pragma unroll
        for(int rr=0;rr<4;rr++){
            int q = quad*4 + rr, s = st*16 + nl;
            attb[q*1024 + ((s + 8*q)&1023)] = f2bf(cc[rr]*0.125f);
        }
    }
    __syncthreads();

    // ---- phase 2: selection + softmax + blend (2 rows/wave via 32-lane groups) ----
    {
        int g = lane>>5, li = lane&31;
        int q = wave*2 + g;
        int qg = q0 + q;
        int slimit = causal ? qg : 1023;
        short* rowp = attb + q*1024;
        unsigned mv[32];
        unsigned mk = 0u;
        #pragma unroll
        for(int t=0;t<2;t++){
            int sb = li*16 + t*512;
            int p0 = (sb + 8*q) & 1023;
            short8 c0 = *(const short8*)(rowp + p0);
            short8 c1 = *(const short8*)(rowp + ((p0+8)&1023));
            #pragma unroll
            for(int j=0;j<8;j++){
                unsigned k0 = (sb+j   <= slimit) ? bkey((unsigned)(unsigned short)c0[j]) : 0u;
                unsigned k1 = (sb+8+j <= slimit) ? bkey((unsigned)(unsigned short)c1[j]) : 0u;
                mv[t*16+j]   = k0; mk = k0>mk?k0:mk;
                mv[t*16+8+j] = k1; mk = k1>mk?k1:mk;
            }
        }
        #pragma unroll
        for(int j=0;j<32;j++) asm volatile("" : "+v"(mv[j]));
        #pragma unroll
        for(int o=1;o<=16;o<<=1){ unsigned tt=__shfl_xor(mk,o,64); mk = tt>mk?tt:mk; }
        unsigned lo=0u, hi=mk+1u;
        for(int it=0; it<16; ++it){
            unsigned mid = lo + ((hi-lo)>>1);
            unsigned cnt = 0u;
            #pragma unroll
            for(int j=0;j<32;j++) cnt += (mv[j] >= mid) ? 1u : 0u;
            #pragma unroll
            for(int o=1;o<=16;o<<=1) cnt += __shfl_xor(cnt,o,64);
            bool ge = (cnt >= 128u);
            bool eq = (cnt == 128u);
            lo = ge ? mid : lo;
            hi = ge ? (eq ? mid+1u : hi) : mid;
        }
        float mxf = key2f(mk);
        float sm = 0.f;
        #pragma unroll
        for(int j=0;j<32;j++){
            unsigned k = mv[j];
            float e = (k >= lo && k != 0u) ? __expf(key2f(k)-mxf) : 0.f;
            mv[j] = __builtin_bit_cast(unsigned, e);
            sm += e;
        }
        #pragma unroll
        for(int o=1;o<=16;o<<=1) sm += __shfl_xor(sm,o,64);
        float inv = 0.5f/sm;   // (1-gw)=0.5
        const short* grow = graph + (long)qg*1024;
        #pragma unroll
        for(int t=0;t<2;t++){
            int sb = li*16 + t*512;
            short8 g0 = *(const short8*)(grow + sb);
            short8 g1 = *(const short8*)(grow + sb + 8);
            short8 o0, o1;
            #pragma unroll
            for(int j=0;j<8;j++){
                float gv0 = __builtin_bit_cast(float, ((unsigned)(unsigned short)g0[j])<<16);
                float gv1 = __builtin_bit_cast(float, ((unsigned)(unsigned short)g1[j])<<16);
                float e0 = __builtin_bit_cast(float, mv[t*16+j]);
                float e1 = __builtin_bit_cast(float, mv[t*16+8+j]);
                o0[j] = f2bf(0.5f*gv0 + e0*inv);
                o1[j] = f2bf(0.5f*gv1 + e1*inv);
            }
            int p0 = (sb + 8*q) & 1023;
            *(short8*)(rowp + p0) = o0;
            *(short8*)(rowp + ((p0+8)&1023)) = o1;
        }
    }
    __syncthreads();

    // ---- phase 3: ctx = att @ V, split over s-halves (sh), v-quarters (vh) ----
    int vh = wave & 3, sh = wave >> 2;
    int v0 = vh*16;
    const short* Vp = Vt + ((long)hn*KD_ + v0 + nl)*S_;
    floatx4 o4 = (floatx4){0.f,0.f,0.f,0.f};
    int arow = nl;
    int sbase = sh*512;
    for(int s0=sbase; s0<sbase+512; s0+=32){
        int cs = (s0 + quad*8 + 8*arow) & 1023;
        short8 ap = *(const short8*)(attb + arow*1024 + cs);
        short8 bv = *(const short8*)(Vp + s0 + quad*8);
        o4 = __builtin_amdgcn_mfma_f32_16x16x32_bf16(ap,bv,o4,0,0,0);
    }
    if(sh==1){
        #pragma unroll
        for(int rr=0;rr<4;rr++) pbuf[(quad*4+rr)*68 + v0 + nl] = o4[rr];
    }
    __syncthreads();
    if(sh==0){
        #pragma unroll
        for(int rr=0;rr<4;rr++){
            int q = quad*4 + rr;
            float v = o4[rr] + pbuf[q*68 + v0 + nl];
            ctx[ ((long)(n*S_ + q0 + q))*512 + h*KD_ + v0 + nl ] = f2bf(v);
        }
    }
}

// ---------------- LayerNorm(x + res) ----------------
__global__ __launch_bounds__(256) void ln_kernel(const float* __restrict__ x, const float* __restrict__ res,
                                                 float* __restrict__ outf, short* __restrict__ outb){
    long row = blockIdx.x;
    const float* xr = x + row*D_;
    const float* rr = res + row*D_;
    int tid = threadIdx.x, wave = tid>>6, lane = tid&63;
    float t0 = xr[tid] + rr[tid];
    float t1 = xr[tid+256] + rr[tid+256];
    float s = t0 + t1, s2 = t0*t0 + t1*t1;
    __shared__ float red[8];
    s = wred_addf(s); s2 = wred_addf(s2);
    if(lane==0){ red[wave] = s; red[4+wave] = s2; }
    __syncthreads();
    s  = red[0]+red[1]+red[2]+red[3];
    s2 = red[4]+red[5]+red[6]+red[7];
    float mean = s*(1.f/512.f);
    float var = s2*(1.f/512.f) - mean*mean;
    float rs = rsqrtf(var + 1e-5f);
    float o0 = (t0-mean)*rs, o1 = (t1-mean)*rs;
    if(outf){ outf[row*D_+tid] = o0; outf[row*D_+tid+256] = o1; }
    if(outb){ outb[row*D_+tid] = f2bf(o0); outb[row*D_+tid+256] = f2bf(o1); }
}

extern "C" void kernel_launch(void* const* d_in, const int* in_sizes, int n_in,
                              void* d_out, int out_size, void* d_ws, size_t ws_size,
                              hipStream_t stream)
{
    const float* z         = (const float*)d_in[0];
    const float* y         = (const float*)d_in[1];
    const float* graph_dec = (const float*)d_in[2];
    const float* graph_enc = (const float*)d_in[3];
    const float* dec_Wk = (const float*)d_in[4];  const float* dec_bk = (const float*)d_in[5];
    const float* dec_Wv = (const float*)d_in[6];  const float* dec_bv = (const float*)d_in[7];
    const float* dec_Wo = (const float*)d_in[8];  const float* dec_bo = (const float*)d_in[9];
    const float* enc_Wk = (const float*)d_in[10]; const float* enc_bk = (const float*)d_in[11];
    const float* enc_Wq = (const float*)d_in[12]; const float* enc_bq = (const float*)d_in[13];
    const float* enc_Wv = (const float*)d_in[14]; const float* enc_bv = (const float*)d_in[15];
    const float* enc_Wo = (const float*)d_in[16]; const float* enc_bo = (const float*)d_in[17];
    const float* fc_W1  = (const float*)d_in[18]; const float* fc_b1  = (const float*)d_in[19];
    const float* fc_W2  = (const float*)d_in[20]; const float* fc_b2  = (const float*)d_in[21];

    char* ws = (char*)d_ws;
    short* gdec  = (short*)(ws + 0x0000000);
    short* genc  = (short*)(ws + 0x0400000);
    short* y_bf  = (short*)(ws + 0x0800000);
    short* z_bf  = (short*)(ws + 0x0C00000);
    short* Kdec  = (short*)(ws + 0x1000000);
    short* Vtdec = (short*)(ws + 0x1400000);
    short* Kenc  = (short*)(ws + 0x1800000);
    short* Vtenc = (short*)(ws + 0x1C00000);
    short* Qenc  = (short*)(ws + 0x2000000);
    short* ctx   = (short*)(ws + 0x2400000);
    float* tmp   = (float*)(ws + 0x2800000);
    float* hbuf  = (float*)(ws + 0x3000000);
    short* h_bf  = (short*)(ws + 0x3800000);
    float* h2    = (float*)(ws + 0x3C00000);
    short* h2_bf = (short*)(ws + 0x4400000);
    short* fc1   = (short*)(ws + 0x4800000);
    short* wKVd  = (short*)(ws + 0x5800000);
    short* wKVe  = (short*)(ws + 0x5900000);
    short* wQet  = (short*)(ws + 0x5A00000);
    short* wOdt  = (short*)(ws + 0x5A80000);
    short* wOet  = (short*)(ws + 0x5B00000);
    short* wF1t  = (short*)(ws + 0x5B80000);
    short* wF2t  = (short*)(ws + 0x5D80000);
    float* outp  = (float*)d_out;

    dim3 B(256);
    wtrans5_kernel<<<dim3(2,16,40),B,0,stream>>>(dec_Wk, dec_Wv, enc_Wk, enc_Wv, enc_Wq, wKVd, wKVe, wQet);
    wtrans4_kernel<<<dim3(2560),B,0,stream>>>(dec_Wo, enc_Wo, fc_W1, fc_W2, wOdt, wOet, wF1t, wF2t);
    cvt2_kernel<<<dim3(2048,2),B,0,stream>>>(y, z, y_bf, z_bf);
    graph_softmax_kernel<<<dim3(1024,2),B,0,stream>>>(graph_dec, graph_enc, gdec, genc);
    // decoder stage
    gemm_kv_kernel<<<dim3(64,2,8),B,0,stream>>>(y_bf, wKVd, dec_bk, dec_bv, Kdec, Vtdec);
    attn_kernel<<<dim3(32,64),dim3(512),0,stream>>>(Kdec, Kdec, Vtdec, gdec, ctx, 1);
    gemm_big_kernel<64,128,0,0><<<dim3(64,4),B,0,stream>>>(ctx, wOdt, dec_bo, tmp, 4096, 512, 512);
    ln_kernel<<<dim3(4096),B,0,stream>>>(tmp, y, hbuf, h_bf);
    // encoder-decoder stage
    gemm_kv_kernel<<<dim3(64,2,8),B,0,stream>>>(z_bf, wKVe, enc_bk, enc_bv, Kenc, Vtenc);
    gemm_kernel<<<dim3(64,1,8),B,0,stream>>>(h_bf, wQet, enc_bq, Qenc, 512, 64*512, 64);
    attn_kernel<<<dim3(32,64),dim3(512),0,stream>>>(Qenc, Kenc, Vtenc, genc, ctx, 0);
    gemm_big_kernel<64,128,0,0><<<dim3(64,4),B,0,stream>>>(ctx, wOet, enc_bo, tmp, 4096, 512, 512);
    ln_kernel<<<dim3(4096),B,0,stream>>>(tmp, hbuf, h2, h2_bf);
    // MLP
    gemm_big_kernel<128,128,1,1><<<dim3(32,16),B,0,stream>>>(h2_bf, wF1t, fc_b1, fc1, 4096, 2048, 512);
    gemm_big_kernel<64,128,0,0><<<dim3(64,4),B,0,stream>>>(fc1, wF2t, fc_b2, tmp, 4096, 512, 2048);
    ln_kernel<<<dim3(4096),B,0,stream>>>(tmp, h2, outp, (short*)0);
}

// Round 11
// 428.611 us; speedup vs baseline: 1.5725x; 1.0893x over previous
//
#include <hip/hip_runtime.h>
#include <stdint.h>

typedef short short8 __attribute__((ext_vector_type(8)));
typedef short short4v __attribute__((ext_vector_type(4)));
typedef float floatx4 __attribute__((ext_vector_type(4)));

#define H_  8
#define NB_ 4      // batch N
#define S_  1024
#define D_  512
#define KD_ 64

__device__ __forceinline__ short f2bf(float f){
    unsigned u = __builtin_bit_cast(unsigned, f);
    u += 0x7fffu + ((u>>16)&1u);
    return (short)(u>>16);
}
__device__ __forceinline__ float wred_addf(float x){
    #pragma unroll
    for(int o=32;o>0;o>>=1) x += __shfl_xor(x,o,64);
    return x;
}
__device__ __forceinline__ float wred_maxf(float x){
    #pragma unroll
    for(int o=32;o>0;o>>=1) x = fmaxf(x,__shfl_xor(x,o,64));
    return x;
}
// monotone 16-bit key for a bf16 pattern; key 0 only from masked entries
__device__ __forceinline__ unsigned bkey(unsigned u){
    return (u & 0x8000u) ? ((~u) & 0xffffu) : (u | 0x8000u);
}
__device__ __forceinline__ float key2f(unsigned k){
    unsigned u = (k & 0x8000u) ? (k & 0x7fffu) : ((~k) & 0xffffu);
    return __builtin_bit_cast(float, u<<16);
}

// ---------------- fused fp32 -> bf16 for y and z ----------------
__global__ __launch_bounds__(256) void cvt2_kernel(const float* __restrict__ a, const float* __restrict__ b,
                                                   short* __restrict__ oa, short* __restrict__ ob){
    const float* in = blockIdx.y ? b : a;
    short* out = blockIdx.y ? ob : oa;
    int i = (blockIdx.x*256 + threadIdx.x)*4;
    floatx4 v = *(const floatx4*)(in + i);
    short4v r;
    #pragma unroll
    for(int j=0;j<4;j++) r[j] = f2bf(v[j]);
    *(short4v*)(out + i) = r;
}

// ---------------- fused transpose of the 5 per-head [512][64] weights ----------------
__global__ __launch_bounds__(256) void wtrans5_kernel(
    const float* __restrict__ dWk, const float* __restrict__ dWv,
    const float* __restrict__ eWk, const float* __restrict__ eWv, const float* __restrict__ eWq,
    short* __restrict__ wKVd, short* __restrict__ wKVe, short* __restrict__ wQet)
{
    __shared__ float t[32][33];
    int zz = blockIdx.z; int w = zz>>3, h = zz&7;
    const float* src; short* dst;
    if(w==0){ src = dWk + h*32768; dst = wKVd + h*65536; }
    else if(w==1){ src = dWv + h*32768; dst = wKVd + h*65536 + 32768; }
    else if(w==2){ src = eWk + h*32768; dst = wKVe + h*65536; }
    else if(w==3){ src = eWv + h*32768; dst = wKVe + h*65536 + 32768; }
    else { src = eWq + h*32768; dst = wQet + h*32768; }
    const int R = 512, C = 64;
    int c0 = blockIdx.x*32, r0 = blockIdx.y*32;
    int tid = threadIdx.x;
    int r = tid>>3, cq = (tid&7)*4;
    #pragma unroll
    for(int i=0;i<4;i++) t[r][cq+i] = src[(r0+r)*C + c0+cq+i];
    __syncthreads();
    int c = tid>>3, rq = (tid&7)*4;
    #pragma unroll
    for(int i=0;i<4;i++) dst[(c0+c)*R + r0+rq+i] = f2bf(t[rq+i][c]);
}

// ---------------- fused transpose of Wo(dec), Wo(enc), fc_W1, fc_W2 ----------------
__global__ __launch_bounds__(256) void wtrans4_kernel(
    const float* __restrict__ dWo, const float* __restrict__ eWo,
    const float* __restrict__ W1, const float* __restrict__ W2,
    short* __restrict__ oWod, short* __restrict__ oWoe,
    short* __restrict__ oW1, short* __restrict__ oW2)
{
    __shared__ float t[32][33];
    int id = blockIdx.x;
    const float* src; short* dst; int R, C, c0, r0;
    if(id < 512){
        src = (id<256)? dWo : eWo; dst = (id<256)? oWod : oWoe;
        int tt = id & 255; R = 512; C = 512;
        c0 = (tt&15)*32; r0 = (tt>>4)*32;
    } else if(id < 1536){
        src = W1; dst = oW1; int tt = id - 512; R = 512; C = 2048;
        c0 = (tt&63)*32; r0 = (tt>>6)*32;
    } else {
        src = W2; dst = oW2; int tt = id - 1536; R = 2048; C = 512;
        c0 = (tt&15)*32; r0 = (tt>>4)*32;
    }
    int tid = threadIdx.x;
    int r = tid>>3, cq = (tid&7)*4;
    #pragma unroll
    for(int i=0;i<4;i++) t[r][cq+i] = src[(long)(r0+r)*C + c0+cq+i];
    __syncthreads();
    int c = tid>>3, rq = (tid&7)*4;
    #pragma unroll
    for(int i=0;i<4;i++) dst[(long)(c0+c)*R + r0+rq+i] = f2bf(t[rq+i][c]);
}

// ---------------- row softmax of the two graphs -> bf16 ----------------
__global__ __launch_bounds__(256) void graph_softmax_kernel(const float* __restrict__ g0,
                                                            const float* __restrict__ g1,
                                                            short* __restrict__ o0,
                                                            short* __restrict__ o1){
    int row = blockIdx.x;
    const float* g = blockIdx.y ? g1 : g0;
    short* o = blockIdx.y ? o1 : o0;
    const float* gr = g + (long)row*S_;
    short* orow = o + (long)row*S_;
    int tid = threadIdx.x, wave = tid>>6, lane = tid&63;
    __shared__ float red[8];
    float v[4]; float mx = -3.0e38f;
    #pragma unroll
    for(int i=0;i<4;i++){ v[i] = gr[tid + 256*i]; mx = fmaxf(mx, v[i]); }
    mx = wred_maxf(mx);
    if(lane==0) red[wave] = mx;
    __syncthreads();
    mx = fmaxf(fmaxf(red[0],red[1]), fmaxf(red[2],red[3]));
    float s = 0.f;
    #pragma unroll
    for(int i=0;i<4;i++){ v[i] = __expf(v[i]-mx); s += v[i]; }
    s = wred_addf(s);
    if(lane==0) red[4+wave] = s;
    __syncthreads();
    s = red[4]+red[5]+red[6]+red[7];
    float inv = 1.f/s;
    #pragma unroll
    for(int i=0;i<4;i++) orow[tid + 256*i] = f2bf(v[i]*inv);
}

// ---------------- LDS-staged projection GEMM ----------------
// KV=1: Bt = wKV[z][128][512] (64 K rows + 64 V rows); outputs K layout + Vt layout.
// KV=0: Bt = wQ[z][64][512]; output K-style layout only.
template<int KV>
__global__ __launch_bounds__(256) void gemm_proj_kernel(
    const short* __restrict__ A, const short* __restrict__ Bt,
    const float* __restrict__ b1, const float* __restrict__ b2,
    short* __restrict__ o1, short* __restrict__ o2)
{
    constexpr int TN = KV ? 128 : 64;
    constexpr int NI = TN/32;
    __shared__ short As[64*32];
    __shared__ short Bs[TN*32];
    int z = blockIdx.z;
    int m0 = blockIdx.x*64;
    const short* Bb = Bt + (long)z*(TN*512);
    int tid = threadIdx.x, wave = tid>>6, lane = tid&63, quad = lane>>4, nl = lane&15;
    int wm = (wave&1)*32, wn = (wave>>1)*(TN/2);
    floatx4 acc[2][NI];
    #pragma unroll
    for(int i=0;i<2;i++)
        #pragma unroll
        for(int j=0;j<NI;j++) acc[i][j] = (floatx4){0.f,0.f,0.f,0.f};
    int r = tid>>2, c = (tid&3)*8;
    for(int k0=0;k0<512;k0+=32){
        __syncthreads();
        __builtin_amdgcn_global_load_lds(
            (const __attribute__((address_space(1))) unsigned*)(A + (long)(m0 + r)*512 + k0 + c),
            (__attribute__((address_space(3))) unsigned*)((char*)As + wave*1024), 16, 0, 0);
        #pragma unroll
        for(int i=0;i<TN/64;i++)
            __builtin_amdgcn_global_load_lds(
                (const __attribute__((address_space(1))) unsigned*)(Bb + (long)(r + i*64)*512 + k0 + c),
                (__attribute__((address_space(3))) unsigned*)((char*)Bs + i*4096 + wave*1024), 16, 0, 0);
        __syncthreads();
        short8 af[2], bfr[NI];
        #pragma unroll
        for(int i=0;i<2;i++) af[i] = *(const short8*)(As + (wm + i*16 + nl)*32 + quad*8);
        #pragma unroll
        for(int j=0;j<NI;j++) bfr[j] = *(const short8*)(Bs + (wn + j*16 + nl)*32 + quad*8);
        #pragma unroll
        for(int i=0;i<2;i++)
            #pragma unroll
            for(int j=0;j<NI;j++)
                acc[i][j] = __builtin_amdgcn_mfma_f32_16x16x32_bf16(af[i],bfr[j],acc[i][j],0,0,0);
    }
    #pragma unroll
    for(int j=0;j<NI;j++){
        int n = wn + j*16 + nl;
        float bv = (KV && n >= 64) ? b2[z*64 + n - 64] : b1[z*64 + n];
        #pragma unroll
        for(int i=0;i<2;i++){
            #pragma unroll
            for(int rr=0;rr<4;rr++){
                int m = m0 + wm + i*16 + quad*4 + rr;
                float v = acc[i][j][rr] + bv;
                long zb = (long)(z*NB_ + (m>>10));
                if(KV && n >= 64) o2[ (zb*KD_ + (n-64))*S_ + (m&1023) ] = f2bf(v);
                else              o1[ (zb*S_ + (m&1023))*KD_ + n ] = f2bf(v);
            }
        }
    }
}

// ---------------- big MFMA GEMM, m97 pattern ----------------
template<int TM, int TN, int OUTBF, int RELU>
__global__ __launch_bounds__(256) void gemm_big_kernel(
    const short* __restrict__ A, const short* __restrict__ Bt, const float* __restrict__ bias,
    void* __restrict__ out, int M, int N, int K)
{
    __shared__ short As[TM*32];
    __shared__ short Bs[TN*32];
    int m0 = blockIdx.x*TM, n0 = blockIdx.y*TN;
    int tid = threadIdx.x, wave = tid>>6, lane = tid&63, quad = lane>>4, nl = lane&15;
    constexpr int MI = TM/32, NI = TN/32;
    int wm = (wave&1)*(TM/2), wn = (wave>>1)*(TN/2);
    floatx4 acc[MI][NI];
    #pragma unroll
    for(int i=0;i<MI;i++)
        #pragma unroll
        for(int j=0;j<NI;j++) acc[i][j] = (floatx4){0.f,0.f,0.f,0.f};

    int r = tid>>2, c = (tid&3)*8;
    for(int k0=0;k0<K;k0+=32){
        __syncthreads();
        #pragma unroll
        for(int i=0;i<TM/64;i++)
            __builtin_amdgcn_global_load_lds(
                (const __attribute__((address_space(1))) unsigned*)(A + (long)(m0 + r + i*64)*K + k0 + c),
                (__attribute__((address_space(3))) unsigned*)((char*)As + i*4096 + wave*1024),
                16, 0, 0);
        #pragma unroll
        for(int i=0;i<TN/64;i++)
            __builtin_amdgcn_global_load_lds(
                (const __attribute__((address_space(1))) unsigned*)(Bt + (long)(n0 + r + i*64)*K + k0 + c),
                (__attribute__((address_space(3))) unsigned*)((char*)Bs + i*4096 + wave*1024),
                16, 0, 0);
        __syncthreads();
        short8 af[MI], bfr[NI];
        #pragma unroll
        for(int i=0;i<MI;i++) af[i] = *(const short8*)(As + (wm + i*16 + nl)*32 + quad*8);
        #pragma unroll
        for(int j=0;j<NI;j++) bfr[j] = *(const short8*)(Bs + (wn + j*16 + nl)*32 + quad*8);
        #pragma unroll
        for(int i=0;i<MI;i++)
            #pragma unroll
            for(int j=0;j<NI;j++)
                acc[i][j] = __builtin_amdgcn_mfma_f32_16x16x32_bf16(af[i],bfr[j],acc[i][j],0,0,0);
    }
    #pragma unroll
    for(int j=0;j<NI;j++){
        int n = n0 + wn + j*16 + nl;
        float bv = bias[n];
        #pragma unroll
        for(int i=0;i<MI;i++){
            #pragma unroll
            for(int rr=0;rr<4;rr++){
                int m = m0 + wm + i*16 + quad*4 + rr;
                float v = acc[i][j][rr] + bv;
                if(RELU) v = fmaxf(v, 0.f);
                if(OUTBF) ((short*)out)[(long)m*N + n] = f2bf(v);
                else      ((float*)out)[(long)m*N + n] = v;
            }
        }
    }
}

// ---------------- fused attention v7: 16 q-rows/block, 512 threads ----------------
// grid (32, 64): blockIdx.x = hn (XCD swizzle), blockIdx.y = qt. 8 waves.
// Phase 2: one full 64-lane wave per row (16 keys/lane), 2 sequential rows per wave.
// launch_bounds(512,6) -> ~85-reg budget so the 16-key array stays register-resident.
__global__ __launch_bounds__(512,6) void attn_kernel(
    const short* __restrict__ Qb, const short* __restrict__ Kb, const short* __restrict__ Vt,
    const short* __restrict__ graph, short* __restrict__ ctx, int causal)
{
    __shared__ short attb[16*1024];   // 32 KiB
    __shared__ float pbuf[16*68];     // 4.25 KiB
    int hn = blockIdx.x, qt = blockIdx.y;
    int h = hn>>2, n = hn&3;
    int q0 = qt*16;
    int tid=threadIdx.x, wave=tid>>6, lane=tid&63, quad=lane>>4, nl=lane&15;

    // ---- phase 1: scores -> bf16 LDS (rot 8q), 16 real rows ----
    const short* Qp = Qb + ((long)hn*S_ + q0 + nl)*KD_ + quad*8;
    short8 aq0 = *(const short8*)(Qp);
    short8 aq1 = *(const short8*)(Qp + 32);
    const short* Kp = Kb + (long)hn*S_*KD_;
    int stmax = causal ? qt : 63;
    for(int st=wave; st<=stmax; st+=8){
        const short* kp = Kp + (st*16 + nl)*KD_ + quad*8;
        short8 b0 = *(const short8*)(kp);
        short8 b1 = *(const short8*)(kp + 32);
        floatx4 cc = (floatx4){0.f,0.f,0.f,0.f};
        cc = __builtin_amdgcn_mfma_f32_16x16x32_bf16(aq0,b0,cc,0,0,0);
        cc = __builtin_amdgcn_mfma_f32_16x16x32_bf16(aq1,b1,cc,0,0,0);
        #pragma unroll
        for(int rr=0;rr<4;rr++){
            int q = quad*4 + rr, s = st*16 + nl;
            attb[q*1024 + ((s + 8*q)&1023)] = f2bf(cc[rr]*0.125f);
        }
    }
    __syncthreads();

    // ---- phase 2: 2 sequential rows/wave, full 64-lane wave per row, 16 keys/lane ----
    for(int rp=0; rp<2; ++rp){
        int q = wave*2 + rp;
        int qg = q0 + q;
        int slimit = causal ? qg : 1023;
        short* rowp = attb + q*1024;
        int sb = lane*16;
        int p0 = (sb + 8*q) & 1023;
        short8 c0 = *(const short8*)(rowp + p0);
        short8 c1 = *(const short8*)(rowp + ((p0+8)&1023));
        unsigned mv[16];
        unsigned mk = 0u;
        #pragma unroll
        for(int j=0;j<8;j++){
            unsigned k0 = (sb+j   <= slimit) ? bkey((unsigned)(unsigned short)c0[j]) : 0u;
            unsigned k1 = (sb+8+j <= slimit) ? bkey((unsigned)(unsigned short)c1[j]) : 0u;
            mv[j]   = k0; mk = k0>mk?k0:mk;
            mv[8+j] = k1; mk = k1>mk?k1:mk;
        }
        #pragma unroll
        for(int o=32;o>0;o>>=1){ unsigned tt=__shfl_xor(mk,o,64); mk = tt>mk?tt:mk; }
        unsigned lo=0u, hi=mk+1u;
        for(int it=0; it<16; ++it){
            unsigned mid = lo + ((hi-lo)>>1);
            unsigned cnt = 0u;
            #pragma unroll
            for(int j=0;j<16;j++) cnt += (mv[j] >= mid) ? 1u : 0u;
            #pragma unroll
            for(int o=32;o>0;o>>=1) cnt += __shfl_xor(cnt,o,64);
            bool ge = (cnt >= 128u);
            bool eq = (cnt == 128u);
            lo = ge ? mid : lo;
            hi = ge ? (eq ? mid+1u : hi) : mid;
        }
        float mxf = key2f(mk);
        float sm = 0.f;
        #pragma unroll
        for(int j=0;j<16;j++){
            unsigned k = mv[j];
            float e = (k >= lo && k != 0u) ? __expf(key2f(k)-mxf) : 0.f;
            mv[j] = __builtin_bit_cast(unsigned, e);
            sm += e;
        }
        #pragma unroll
        for(int o=32;o>0;o>>=1) sm += __shfl_xor(sm,o,64);
        float inv = 0.5f/sm;   // (1-gw)=0.5
        const short* grow = graph + (long)qg*1024 + sb;
        short8 g0 = *(const short8*)(grow);
        short8 g1 = *(const short8*)(grow + 8);
        short8 o0, o1;
        #pragma unroll
        for(int j=0;j<8;j++){
            float gv0 = __builtin_bit_cast(float, ((unsigned)(unsigned short)g0[j])<<16);
            float gv1 = __builtin_bit_cast(float, ((unsigned)(unsigned short)g1[j])<<16);
            float e0 = __builtin_bit_cast(float, mv[j]);
            float e1 = __builtin_bit_cast(float, mv[8+j]);
            o0[j] = f2bf(0.5f*gv0 + e0*inv);
            o1[j] = f2bf(0.5f*gv1 + e1*inv);
        }
        *(short8*)(rowp + p0) = o0;
        *(short8*)(rowp + ((p0+8)&1023)) = o1;
    }
    __syncthreads();

    // ---- phase 3: ctx = att @ V, split over s-halves (sh), v-quarters (vh) ----
    int vh = wave & 3, sh = wave >> 2;
    int v0 = vh*16;
    const short* Vp = Vt + ((long)hn*KD_ + v0 + nl)*S_;
    floatx4 o4 = (floatx4){0.f,0.f,0.f,0.f};
    int arow = nl;
    int sbase = sh*512;
    for(int s0=sbase; s0<sbase+512; s0+=32){
        int cs = (s0 + quad*8 + 8*arow) & 1023;
        short8 ap = *(const short8*)(attb + arow*1024 + cs);
        short8 bv = *(const short8*)(Vp + s0 + quad*8);
        o4 = __builtin_amdgcn_mfma_f32_16x16x32_bf16(ap,bv,o4,0,0,0);
    }
    if(sh==1){
        #pragma unroll
        for(int rr=0;rr<4;rr++) pbuf[(quad*4+rr)*68 + v0 + nl] = o4[rr];
    }
    __syncthreads();
    if(sh==0){
        #pragma unroll
        for(int rr=0;rr<4;rr++){
            int q = quad*4 + rr;
            float v = o4[rr] + pbuf[q*68 + v0 + nl];
            ctx[ ((long)(n*S_ + q0 + q))*512 + h*KD_ + v0 + nl ] = f2bf(v);
        }
    }
}

// ---------------- LayerNorm(x + res) ----------------
__global__ __launch_bounds__(256) void ln_kernel(const float* __restrict__ x, const float* __restrict__ res,
                                                 float* __restrict__ outf, short* __restrict__ outb){
    long row = blockIdx.x;
    const float* xr = x + row*D_;
    const float* rr = res + row*D_;
    int tid = threadIdx.x, wave = tid>>6, lane = tid&63;
    float t0 = xr[tid] + rr[tid];
    float t1 = xr[tid+256] + rr[tid+256];
    float s = t0 + t1, s2 = t0*t0 + t1*t1;
    __shared__ float red[8];
    s = wred_addf(s); s2 = wred_addf(s2);
    if(lane==0){ red[wave] = s; red[4+wave] = s2; }
    __syncthreads();
    s  = red[0]+red[1]+red[2]+red[3];
    s2 = red[4]+red[5]+red[6]+red[7];
    float mean = s*(1.f/512.f);
    float var = s2*(1.f/512.f) - mean*mean;
    float rs = rsqrtf(var + 1e-5f);
    float o0 = (t0-mean)*rs, o1 = (t1-mean)*rs;
    if(outf){ outf[row*D_+tid] = o0; outf[row*D_+tid+256] = o1; }
    if(outb){ outb[row*D_+tid] = f2bf(o0); outb[row*D_+tid+256] = f2bf(o1); }
}

extern "C" void kernel_launch(void* const* d_in, const int* in_sizes, int n_in,
                              void* d_out, int out_size, void* d_ws, size_t ws_size,
                              hipStream_t stream)
{
    const float* z         = (const float*)d_in[0];
    const float* y         = (const float*)d_in[1];
    const float* graph_dec = (const float*)d_in[2];
    const float* graph_enc = (const float*)d_in[3];
    const float* dec_Wk = (const float*)d_in[4];  const float* dec_bk = (const float*)d_in[5];
    const float* dec_Wv = (const float*)d_in[6];  const float* dec_bv = (const float*)d_in[7];
    const float* dec_Wo = (const float*)d_in[8];  const float* dec_bo = (const float*)d_in[9];
    const float* enc_Wk = (const float*)d_in[10]; const float* enc_bk = (const float*)d_in[11];
    const float* enc_Wq = (const float*)d_in[12]; const float* enc_bq = (const float*)d_in[13];
    const float* enc_Wv = (const float*)d_in[14]; const float* enc_bv = (const float*)d_in[15];
    const float* enc_Wo = (const float*)d_in[16]; const float* enc_bo = (const float*)d_in[17];
    const float* fc_W1  = (const float*)d_in[18]; const float* fc_b1  = (const float*)d_in[19];
    const float* fc_W2  = (const float*)d_in[20]; const float* fc_b2  = (const float*)d_in[21];

    char* ws = (char*)d_ws;
    short* gdec  = (short*)(ws + 0x0000000);
    short* genc  = (short*)(ws + 0x0400000);
    short* y_bf  = (short*)(ws + 0x0800000);
    short* z_bf  = (short*)(ws + 0x0C00000);
    short* Kdec  = (short*)(ws + 0x1000000);
    short* Vtdec = (short*)(ws + 0x1400000);
    short* Kenc  = (short*)(ws + 0x1800000);
    short* Vtenc = (short*)(ws + 0x1C00000);
    short* Qenc  = (short*)(ws + 0x2000000);
    short* ctx   = (short*)(ws + 0x2400000);
    float* tmp   = (float*)(ws + 0x2800000);
    float* hbuf  = (float*)(ws + 0x3000000);
    short* h_bf  = (short*)(ws + 0x3800000);
    float* h2    = (float*)(ws + 0x3C00000);
    short* h2_bf = (short*)(ws + 0x4400000);
    short* fc1   = (short*)(ws + 0x4800000);
    short* wKVd  = (short*)(ws + 0x5800000);
    short* wKVe  = (short*)(ws + 0x5900000);
    short* wQet  = (short*)(ws + 0x5A00000);
    short* wOdt  = (short*)(ws + 0x5A80000);
    short* wOet  = (short*)(ws + 0x5B00000);
    short* wF1t  = (short*)(ws + 0x5B80000);
    short* wF2t  = (short*)(ws + 0x5D80000);
    float* outp  = (float*)d_out;

    dim3 B(256);
    wtrans5_kernel<<<dim3(2,16,40),B,0,stream>>>(dec_Wk, dec_Wv, enc_Wk, enc_Wv, enc_Wq, wKVd, wKVe, wQet);
    wtrans4_kernel<<<dim3(2560),B,0,stream>>>(dec_Wo, enc_Wo, fc_W1, fc_W2, wOdt, wOet, wF1t, wF2t);
    cvt2_kernel<<<dim3(2048,2),B,0,stream>>>(y, z, y_bf, z_bf);
    graph_softmax_kernel<<<dim3(1024,2),B,0,stream>>>(graph_dec, graph_enc, gdec, genc);
    // decoder stage
    gemm_proj_kernel<1><<<dim3(64,1,8),B,0,stream>>>(y_bf, wKVd, dec_bk, dec_bv, Kdec, Vtdec);
    attn_kernel<<<dim3(32,64),dim3(512),0,stream>>>(Kdec, Kdec, Vtdec, gdec, ctx, 1);
    gemm_big_kernel<64,128,0,0><<<dim3(64,4),B,0,stream>>>(ctx, wOdt, dec_bo, tmp, 4096, 512, 512);
    ln_kernel<<<dim3(4096),B,0,stream>>>(tmp, y, hbuf, h_bf);
    // encoder-decoder stage
    gemm_proj_kernel<1><<<dim3(64,1,8),B,0,stream>>>(z_bf, wKVe, enc_bk, enc_bv, Kenc, Vtenc);
    gemm_proj_kernel<0><<<dim3(64,1,8),B,0,stream>>>(h_bf, wQet, enc_bq, (const float*)0, Qenc, (short*)0);
    attn_kernel<<<dim3(32,64),dim3(512),0,stream>>>(Qenc, Kenc, Vtenc, genc, ctx, 0);
    gemm_big_kernel<64,128,0,0><<<dim3(64,4),B,0,stream>>>(ctx, wOet, enc_bo, tmp, 4096, 512, 512);
    ln_kernel<<<dim3(4096),B,0,stream>>>(tmp, hbuf, h2, h2_bf);
    // MLP
    gemm_big_kernel<128,128,1,1><<<dim3(32,16),B,0,stream>>>(h2_bf, wF1t, fc_b1, fc1, 4096, 2048, 512);
    gemm_big_kernel<64,128,0,0><<<dim3(64,4),B,0,stream>>>(fc1, wF2t, fc_b2, tmp, 4096, 512, 2048);
    ln_kernel<<<dim3(4096),B,0,stream>>>(tmp, h2, outp, (short*)0);
}